// Round 1
// baseline (654.800 us; speedup 1.0000x reference)
//
#include <hip/hip_runtime.h>
#include <math.h>

#define TPB 128
constexpr int  N_LVL = 16;
constexpr unsigned TBL = 1u << 19;          // hash table size per level
constexpr float MOVE_STEP = 1.0f / 4096.0f;

struct LevelParams {
    float scale[N_LVL];
    int   res[N_LVL];
    int   dense[N_LVL];
};

// out[j] = sum_i act[i] * W[i*OUT+j]
// A points at &lds_act[tid]; feature i lives at A[i*TPB] (feature-major, conflict-free).
// W accesses are wave-uniform -> scalar loads (s_load) on gfx950.
template<int IN, int OUT>
__device__ __forceinline__ void dense_layer(const float* __restrict__ W,
                                            const float* __restrict__ A,
                                            float* __restrict__ out)
{
#pragma unroll
    for (int j = 0; j < OUT; ++j) out[j] = 0.f;
#pragma unroll 4
    for (int i = 0; i < IN; ++i) {
        const float a = A[i * TPB];
#pragma unroll
        for (int j = 0; j < OUT; ++j)
            out[j] = fmaf(a, W[i * OUT + j], out[j]);
    }
}

template<int OUT, bool RELU>
__device__ __forceinline__ void store_act(float* __restrict__ A, const float* __restrict__ v)
{
#pragma unroll
    for (int j = 0; j < OUT; ++j)
        A[j * TPB] = RELU ? fmaxf(v[j], 0.f) : v[j];
}

__global__ __launch_bounds__(TPB) void dngp_fwd(
    const float* __restrict__ g_pos, const float* __restrict__ g_t,
    const float* __restrict__ g_dir, const float* __restrict__ g_tab,
    const float* __restrict__ Ww0, const float* __restrict__ Ww1, const float* __restrict__ Ww2,
    const float* __restrict__ Wb0, const float* __restrict__ Wb1,
    const float* __restrict__ Wh0, const float* __restrict__ Wh1, const float* __restrict__ Wh2,
    float* __restrict__ g_out, int N, LevelParams lp)
{
    __shared__ float s_act[64 * TPB];       // 32 KB: feature-major activations
    const int tid = threadIdx.x;
    const int n = blockIdx.x * TPB + tid;
    if (n >= N) return;
    float* __restrict__ A = s_act + tid;

    const float px = g_pos[3 * n + 0];
    const float py = g_pos[3 * n + 1];
    const float pz = g_pos[3 * n + 2];
    const float tt = g_t[n];

    // ---------------- frequency encoding: 4 dims x 4 freqs x (sin,cos) = 32 ----------------
    {
        const float xin[4] = { px, py, pz, tt };
        const float PI_F = 3.14159265358979323846f;   // rounds to f32 pi, matches jnp
#pragma unroll
        for (int d = 0; d < 4; ++d) {
#pragma unroll
            for (int k = 0; k < 4; ++k) {
                float s, c;
                sincosf(xin[d] * (PI_F * (float)(1 << k)), &s, &c);
                A[(d * 8 + k)     * TPB] = s;
                A[(d * 8 + 4 + k) * TPB] = c;
            }
        }
    }

    float h[64];

    // ---------------- warp ("wrap") MLP: 32 -> 64 -> 64 -> 3 ----------------
    dense_layer<32, 64>(Ww0, A, h); store_act<64, true>(A, h);
    dense_layer<64, 64>(Ww1, A, h); store_act<64, true>(A, h);
    float off[3];
    dense_layer<64, 3>(Ww2, A, off);

    const float mx = px + off[0] * MOVE_STEP;
    const float my = py + off[1] * MOVE_STEP;
    const float mz = pz + off[2] * MOVE_STEP;
    const float xn[3] = { (mx + 1.5f) / 3.0f, (my + 1.5f) / 3.0f, (mz + 1.5f) / 3.0f };
    const bool sel = xn[0] > 0.f && xn[0] < 1.f &&
                     xn[1] > 0.f && xn[1] < 1.f &&
                     xn[2] > 0.f && xn[2] < 1.f;

    // ---------------- multires hash encoding: 16 levels x 2 feats ----------------
    for (int l = 0; l < N_LVL; ++l) {
        const float scale = lp.scale[l];
        const int res = lp.res[l];
        float fr[3]; int c0[3];
#pragma unroll
        for (int d = 0; d < 3; ++d) {
            const float p = xn[d] * scale + 0.5f;
            const float fl = floorf(p);
            fr[d] = p - fl;
            c0[d] = (int)fl;
        }
        const float* __restrict__ tbl = g_tab + (size_t)l * (size_t)(TBL * 2);
        float f0 = 0.f, f1 = 0.f;
        if (lp.dense[l]) {
#pragma unroll
            for (int c = 0; c < 8; ++c) {
                const int ci = (c >> 2) & 1, cj = (c >> 1) & 1, ck = c & 1;
                const unsigned idx = (unsigned)((c0[0] + ci) + res * ((c0[1] + cj) + res * (c0[2] + ck)));
                const float2 f = *reinterpret_cast<const float2*>(tbl + (size_t)idx * 2);
                const float w = (ci ? fr[0] : 1.f - fr[0])
                              * (cj ? fr[1] : 1.f - fr[1])
                              * (ck ? fr[2] : 1.f - fr[2]);
                f0 = fmaf(w, f.x, f0);
                f1 = fmaf(w, f.y, f1);
            }
        } else {
#pragma unroll
            for (int c = 0; c < 8; ++c) {
                const int ci = (c >> 2) & 1, cj = (c >> 1) & 1, ck = c & 1;
                const unsigned hx = (unsigned)(c0[0] + ci);
                const unsigned hy = (unsigned)(c0[1] + cj) * 2654435761u;
                const unsigned hz = (unsigned)(c0[2] + ck) * 805459861u;
                const unsigned idx = (hx ^ hy ^ hz) & (TBL - 1u);
                const float2 f = *reinterpret_cast<const float2*>(tbl + (size_t)idx * 2);
                const float w = (ci ? fr[0] : 1.f - fr[0])
                              * (cj ? fr[1] : 1.f - fr[1])
                              * (ck ? fr[2] : 1.f - fr[2]);
                f0 = fmaf(w, f.x, f0);
                f1 = fmaf(w, f.y, f1);
            }
        }
        A[(2 * l)     * TPB] = f0;
        A[(2 * l + 1) * TPB] = f1;
    }

    // ---------------- base MLP: 32 -> 64 -> 16 ----------------
    dense_layer<32, 64>(Wb0, A, h); store_act<64, true>(A, h);
    dense_layer<64, 16>(Wb1, A, h);

    const float density = sel ? expf(h[0] - 1.0f) : 0.0f;

    // stash geo (h[1..15]) into LDS slots 16..30 AFTER writing SH into 0..15
    float geo[15];
#pragma unroll
    for (int j = 0; j < 15; ++j) geo[j] = h[1 + j];

    // ---------------- SH degree-4 encoding of normalized direction ----------------
    {
        const float ddx = g_dir[3 * n + 0];
        const float ddy = g_dir[3 * n + 1];
        const float ddz = g_dir[3 * n + 2];
        const float nrm = sqrtf(ddx * ddx + ddy * ddy + ddz * ddz);
        const float x = ddx / nrm, y = ddy / nrm, z = ddz / nrm;
        const float xy = x * y, yz = y * z, xz = x * z;
        const float x2 = x * x, y2 = y * y, z2 = z * z;
        float sh[16];
        sh[0]  = 0.28209479177387814f;
        sh[1]  = -0.48860251190291987f * y;
        sh[2]  = 0.48860251190291987f * z;
        sh[3]  = -0.48860251190291987f * x;
        sh[4]  = 1.0925484305920792f * xy;
        sh[5]  = -1.0925484305920792f * yz;
        sh[6]  = 0.94617469575756f * z2 - 0.31539156525252f;
        sh[7]  = -1.0925484305920792f * xz;
        sh[8]  = 0.5462742152960396f * (x2 - y2);
        sh[9]  = 0.5900435899266435f * y * (y2 - 3.0f * x2);
        sh[10] = 2.890611442640554f * xy * z;
        sh[11] = 0.4570457994644657f * y * (1.0f - 5.0f * z2);
        sh[12] = 0.3731763325901154f * z * (5.0f * z2 - 3.0f);
        sh[13] = 0.4570457994644657f * x * (1.0f - 5.0f * z2);
        sh[14] = 1.445305721320277f * z * (x2 - y2);
        sh[15] = 0.5900435899266435f * x * (3.0f * y2 - x2);
#pragma unroll
        for (int j = 0; j < 16; ++j) A[j * TPB] = sh[j];
#pragma unroll
        for (int j = 0; j < 15; ++j) A[(16 + j) * TPB] = geo[j];
    }

    // ---------------- head MLP: 31 -> 64 -> 64 -> 3, sigmoid ----------------
    dense_layer<31, 64>(Wh0, A, h); store_act<64, true>(A, h);
    dense_layer<64, 64>(Wh1, A, h); store_act<64, true>(A, h);
    float rgb[3];
    dense_layer<64, 3>(Wh2, A, rgb);

    float4 o;
    o.x = 1.0f / (1.0f + expf(-rgb[0]));
    o.y = 1.0f / (1.0f + expf(-rgb[1]));
    o.z = 1.0f / (1.0f + expf(-rgb[2]));
    o.w = density;
    *reinterpret_cast<float4*>(g_out + (size_t)n * 4) = o;
}

extern "C" void kernel_launch(void* const* d_in, const int* in_sizes, int n_in,
                              void* d_out, int out_size, void* d_ws, size_t ws_size,
                              hipStream_t stream)
{
    const float* g_pos = (const float*)d_in[0];
    const float* g_t   = (const float*)d_in[1];
    const float* g_dir = (const float*)d_in[2];
    const float* g_tab = (const float*)d_in[3];
    const float* Ww0   = (const float*)d_in[4];
    const float* Ww1   = (const float*)d_in[5];
    const float* Ww2   = (const float*)d_in[6];
    const float* Wb0   = (const float*)d_in[7];
    const float* Wb1   = (const float*)d_in[8];
    const float* Wh0   = (const float*)d_in[9];
    const float* Wh1   = (const float*)d_in[10];
    const float* Wh2   = (const float*)d_in[11];
    const int N = in_sizes[0] / 3;

    LevelParams lp;
    const double Bv = exp(log(4096.0 / 16.0) / 15.0);
    for (int l = 0; l < N_LVL; ++l) {
        const double s = 16.0 * pow(Bv, (double)l) - 1.0;
        lp.scale[l] = (float)s;
        const int r = (int)ceil(s) + 1;
        lp.res[l] = r;
        lp.dense[l] = ((long long)r * r * r <= (long long)TBL) ? 1 : 0;
    }

    dim3 grid((N + TPB - 1) / TPB), block(TPB);
    hipLaunchKernelGGL(dngp_fwd, grid, block, 0, stream,
                       g_pos, g_t, g_dir, g_tab,
                       Ww0, Ww1, Ww2, Wb0, Wb1, Wh0, Wh1, Wh2,
                       (float*)d_out, N, lp);
}

// Round 2
// 565.883 us; speedup vs baseline: 1.1571x; 1.1571x over previous
//
#include <hip/hip_runtime.h>
#include <math.h>

#define TPB 128
#define CHUNK 32
constexpr int  N_LVL = 16;
constexpr unsigned TBL = 1u << 19;          // hash table size per level
constexpr float MOVE_STEP = 1.0f / 4096.0f;

struct LevelParams {
    float scale[N_LVL];
    int   res[N_LVL];
    int   dense[N_LVL];
};

// out[j] = sum_i act_in[i] * W[i*OUT+j], staging act_in chunk-by-chunk through
// a 32-slot-per-thread LDS column (so the accumulate loop can stay rolled with
// dynamic LDS indexing, while weight reads stay wave-uniform s_loads).
// RELU applies relu to the inputs as they are staged.
template<int IN, int OUT, bool RELU>
__device__ __forceinline__ void layer(const float* __restrict__ W,
                                      const float* __restrict__ hin,   // IN regs
                                      float* __restrict__ A,           // LDS col (CHUNK slots)
                                      float* __restrict__ out)         // OUT regs
{
#pragma unroll
    for (int j = 0; j < OUT; ++j) out[j] = 0.f;
#pragma unroll
    for (int c = 0; c < IN; c += CHUNK) {
        // stage this chunk (static register indices: c and i are unroll-constants)
#pragma unroll
        for (int i = 0; i < CHUNK; ++i) {
            if (c + i < IN) A[i * TPB] = RELU ? fmaxf(hin[c + i], 0.f) : hin[c + i];
        }
        const int cnt = (IN - c < CHUNK) ? (IN - c) : CHUNK;   // constexpr-foldable
        // rolled accumulate: 1 ds_read + OUT FMAs per iteration, W row via s_load
#pragma unroll 4
        for (int i = 0; i < cnt; ++i) {
            const float a = A[i * TPB];
            const float* __restrict__ Wr = W + (size_t)(c + i) * OUT;
#pragma unroll
            for (int j = 0; j < OUT; ++j)
                out[j] = fmaf(a, Wr[j], out[j]);
        }
    }
}

__global__ __launch_bounds__(TPB, 4) void dngp_fwd(
    const float* __restrict__ g_pos, const float* __restrict__ g_t,
    const float* __restrict__ g_dir, const float* __restrict__ g_tab,
    const float* __restrict__ Ww0, const float* __restrict__ Ww1, const float* __restrict__ Ww2,
    const float* __restrict__ Wb0, const float* __restrict__ Wb1,
    const float* __restrict__ Wh0, const float* __restrict__ Wh1, const float* __restrict__ Wh2,
    float* __restrict__ g_out, int N, LevelParams lp)
{
    __shared__ float s_act[CHUNK * TPB];    // 16 KB: chunked activation staging
    const int tid = threadIdx.x;
    const int n = blockIdx.x * TPB + tid;
    if (n >= N) return;
    float* __restrict__ A = s_act + tid;

    const float px = g_pos[3 * n + 0];
    const float py = g_pos[3 * n + 1];
    const float pz = g_pos[3 * n + 2];
    const float tt = g_t[n];

    // ---------------- frequency encoding: 4 dims x 4 freqs x (sin,cos) = 32 ----------------
    float enc[32];
    {
        const float xin[4] = { px, py, pz, tt };
        const float PI_F = 3.14159265358979323846f;
#pragma unroll
        for (int d = 0; d < 4; ++d) {
#pragma unroll
            for (int k = 0; k < 4; ++k) {
                float s, c;
                sincosf(xin[d] * (PI_F * (float)(1 << k)), &s, &c);
                enc[d * 8 + k]     = s;
                enc[d * 8 + 4 + k] = c;
            }
        }
    }

    float h[64], h2[64];

    // ---------------- warp MLP: 32 -> 64 -> 64 -> 3 ----------------
    layer<32, 64, false>(Ww0, enc, A, h);
    layer<64, 64, true >(Ww1, h,   A, h2);
    float off[3];
    layer<64, 3,  true >(Ww2, h2,  A, off);

    const float mx = px + off[0] * MOVE_STEP;
    const float my = py + off[1] * MOVE_STEP;
    const float mz = pz + off[2] * MOVE_STEP;
    const float xn[3] = { (mx + 1.5f) / 3.0f, (my + 1.5f) / 3.0f, (mz + 1.5f) / 3.0f };
    const bool sel = xn[0] > 0.f && xn[0] < 1.f &&
                     xn[1] > 0.f && xn[1] < 1.f &&
                     xn[2] > 0.f && xn[2] < 1.f;

    // ---------------- multires hash encoding: 16 levels x 2 feats ----------------
    float feat[32];
#pragma unroll 2
    for (int l = 0; l < N_LVL; ++l) {
        const float scale = lp.scale[l];
        const int res = lp.res[l];
        float fr[3]; int c0[3];
#pragma unroll
        for (int d = 0; d < 3; ++d) {
            const float p = xn[d] * scale + 0.5f;
            const float fl = floorf(p);
            fr[d] = p - fl;
            c0[d] = (int)fl;
        }
        const float* __restrict__ tbl = g_tab + (size_t)l * (size_t)(TBL * 2);
        float f0 = 0.f, f1 = 0.f;
        if (lp.dense[l]) {
#pragma unroll
            for (int c = 0; c < 8; ++c) {
                const int ci = (c >> 2) & 1, cj = (c >> 1) & 1, ck = c & 1;
                const unsigned idx = (unsigned)((c0[0] + ci) + res * ((c0[1] + cj) + res * (c0[2] + ck)));
                const float2 f = *reinterpret_cast<const float2*>(tbl + (size_t)idx * 2);
                const float w = (ci ? fr[0] : 1.f - fr[0])
                              * (cj ? fr[1] : 1.f - fr[1])
                              * (ck ? fr[2] : 1.f - fr[2]);
                f0 = fmaf(w, f.x, f0);
                f1 = fmaf(w, f.y, f1);
            }
        } else {
#pragma unroll
            for (int c = 0; c < 8; ++c) {
                const int ci = (c >> 2) & 1, cj = (c >> 1) & 1, ck = c & 1;
                const unsigned hx = (unsigned)(c0[0] + ci);
                const unsigned hy = (unsigned)(c0[1] + cj) * 2654435761u;
                const unsigned hz = (unsigned)(c0[2] + ck) * 805459861u;
                const unsigned idx = (hx ^ hy ^ hz) & (TBL - 1u);
                const float2 f = *reinterpret_cast<const float2*>(tbl + (size_t)idx * 2);
                const float w = (ci ? fr[0] : 1.f - fr[0])
                              * (cj ? fr[1] : 1.f - fr[1])
                              * (ck ? fr[2] : 1.f - fr[2]);
                f0 = fmaf(w, f.x, f0);
                f1 = fmaf(w, f.y, f1);
            }
        }
        feat[2 * l]     = f0;
        feat[2 * l + 1] = f1;
    }

    // ---------------- base MLP: 32 -> 64 -> 16 ----------------
    layer<32, 64, false>(Wb0, feat, A, h);
    float b[16];
    layer<64, 16, true >(Wb1, h,    A, b);

    const float density = sel ? expf(b[0] - 1.0f) : 0.0f;

    // ---------------- SH degree-4 + geo -> head input (31 regs) ----------------
    float hin[31];
    {
        const float ddx = g_dir[3 * n + 0];
        const float ddy = g_dir[3 * n + 1];
        const float ddz = g_dir[3 * n + 2];
        const float nrm = sqrtf(ddx * ddx + ddy * ddy + ddz * ddz);
        const float x = ddx / nrm, y = ddy / nrm, z = ddz / nrm;
        const float xy = x * y, yz = y * z, xz = x * z;
        const float x2 = x * x, y2 = y * y, z2 = z * z;
        hin[0]  = 0.28209479177387814f;
        hin[1]  = -0.48860251190291987f * y;
        hin[2]  = 0.48860251190291987f * z;
        hin[3]  = -0.48860251190291987f * x;
        hin[4]  = 1.0925484305920792f * xy;
        hin[5]  = -1.0925484305920792f * yz;
        hin[6]  = 0.94617469575756f * z2 - 0.31539156525252f;
        hin[7]  = -1.0925484305920792f * xz;
        hin[8]  = 0.5462742152960396f * (x2 - y2);
        hin[9]  = 0.5900435899266435f * y * (y2 - 3.0f * x2);
        hin[10] = 2.890611442640554f * xy * z;
        hin[11] = 0.4570457994644657f * y * (1.0f - 5.0f * z2);
        hin[12] = 0.3731763325901154f * z * (5.0f * z2 - 3.0f);
        hin[13] = 0.4570457994644657f * x * (1.0f - 5.0f * z2);
        hin[14] = 1.445305721320277f * z * (x2 - y2);
        hin[15] = 0.5900435899266435f * x * (3.0f * y2 - x2);
#pragma unroll
        for (int j = 0; j < 15; ++j) hin[16 + j] = b[1 + j];
    }

    // ---------------- head MLP: 31 -> 64 -> 64 -> 3, sigmoid ----------------
    layer<31, 64, false>(Wh0, hin, A, h);
    layer<64, 64, true >(Wh1, h,   A, h2);
    float rgb[3];
    layer<64, 3,  true >(Wh2, h2,  A, rgb);

    float4 o;
    o.x = 1.0f / (1.0f + expf(-rgb[0]));
    o.y = 1.0f / (1.0f + expf(-rgb[1]));
    o.z = 1.0f / (1.0f + expf(-rgb[2]));
    o.w = density;
    *reinterpret_cast<float4*>(g_out + (size_t)n * 4) = o;
}

extern "C" void kernel_launch(void* const* d_in, const int* in_sizes, int n_in,
                              void* d_out, int out_size, void* d_ws, size_t ws_size,
                              hipStream_t stream)
{
    const float* g_pos = (const float*)d_in[0];
    const float* g_t   = (const float*)d_in[1];
    const float* g_dir = (const float*)d_in[2];
    const float* g_tab = (const float*)d_in[3];
    const float* Ww0   = (const float*)d_in[4];
    const float* Ww1   = (const float*)d_in[5];
    const float* Ww2   = (const float*)d_in[6];
    const float* Wb0   = (const float*)d_in[7];
    const float* Wb1   = (const float*)d_in[8];
    const float* Wh0   = (const float*)d_in[9];
    const float* Wh1   = (const float*)d_in[10];
    const float* Wh2   = (const float*)d_in[11];
    const int N = in_sizes[0] / 3;

    LevelParams lp;
    const double Bv = exp(log(4096.0 / 16.0) / 15.0);
    for (int l = 0; l < N_LVL; ++l) {
        const double s = 16.0 * pow(Bv, (double)l) - 1.0;
        lp.scale[l] = (float)s;
        const int r = (int)ceil(s) + 1;
        lp.res[l] = r;
        lp.dense[l] = ((long long)r * r * r <= (long long)TBL) ? 1 : 0;
    }

    dim3 grid((N + TPB - 1) / TPB), block(TPB);
    hipLaunchKernelGGL(dngp_fwd, grid, block, 0, stream,
                       g_pos, g_t, g_dir, g_tab,
                       Ww0, Ww1, Ww2, Wb0, Wb1, Wh0, Wh1, Wh2,
                       (float*)d_out, N, lp);
}

// Round 3
// 542.394 us; speedup vs baseline: 1.2072x; 1.0433x over previous
//
#include <hip/hip_runtime.h>
#include <math.h>

#define TPB   128     // MLP kernels
#define HTPB  256     // hash kernels
#define CHUNK 32
constexpr int  N_LVL = 16;
constexpr unsigned TBL = 1u << 19;
constexpr float MOVE_STEP = 1.0f / 4096.0f;

struct LevelParams {
    float scale[N_LVL];
    int   res[N_LVL];
    int   dense[N_LVL];
};

// out[j] = sum_i act_in[i] * W[i*OUT+j], staging act_in chunk-by-chunk through
// a CHUNK-slot-per-thread LDS column. Weight reads stay wave-uniform s_loads.
template<int IN, int OUT, bool RELU>
__device__ __forceinline__ void layer(const float* __restrict__ W,
                                      const float* __restrict__ hin,
                                      float* __restrict__ A,
                                      float* __restrict__ out)
{
#pragma unroll
    for (int j = 0; j < OUT; ++j) out[j] = 0.f;
#pragma unroll
    for (int c = 0; c < IN; c += CHUNK) {
#pragma unroll
        for (int i = 0; i < CHUNK; ++i) {
            if (c + i < IN) A[i * TPB] = RELU ? fmaxf(hin[c + i], 0.f) : hin[c + i];
        }
        const int cnt = (IN - c < CHUNK) ? (IN - c) : CHUNK;
#pragma unroll 4
        for (int i = 0; i < cnt; ++i) {
            const float a = A[i * TPB];
            const float* __restrict__ Wr = W + (size_t)(c + i) * OUT;
#pragma unroll
            for (int j = 0; j < OUT; ++j)
                out[j] = fmaf(a, Wr[j], out[j]);
        }
    }
}

// ---------------------------------------------------------------------------
// Kernel 1: freq encode + warp MLP -> xn planes
// ---------------------------------------------------------------------------
__global__ __launch_bounds__(TPB, 4) void k_warp(
    const float* __restrict__ g_pos, const float* __restrict__ g_t,
    const float* __restrict__ Ww0, const float* __restrict__ Ww1,
    const float* __restrict__ Ww2,
    float* __restrict__ xn0, float* __restrict__ xn1, float* __restrict__ xn2,
    int N)
{
    __shared__ float s_act[CHUNK * TPB];
    const int tid = threadIdx.x;
    const int n = blockIdx.x * TPB + tid;
    if (n >= N) return;
    float* __restrict__ A = s_act + tid;

    const float px = g_pos[3 * n + 0];
    const float py = g_pos[3 * n + 1];
    const float pz = g_pos[3 * n + 2];
    const float tt = g_t[n];

    float enc[32];
    {
        const float xin[4] = { px, py, pz, tt };
        const float PI_F = 3.14159265358979323846f;
#pragma unroll
        for (int d = 0; d < 4; ++d)
#pragma unroll
            for (int k = 0; k < 4; ++k) {
                float s, c;
                sincosf(xin[d] * (PI_F * (float)(1 << k)), &s, &c);
                enc[d * 8 + k]     = s;
                enc[d * 8 + 4 + k] = c;
            }
    }

    float h[64], h2[64], off[3];
    layer<32, 64, false>(Ww0, enc, A, h);
    layer<64, 64, true >(Ww1, h,   A, h2);
    layer<64, 3,  true >(Ww2, h2,  A, off);

    xn0[n] = (px + off[0] * MOVE_STEP + 1.5f) / 3.0f;
    xn1[n] = (py + off[1] * MOVE_STEP + 1.5f) / 3.0f;
    xn2[n] = (pz + off[2] * MOVE_STEP + 1.5f) / 3.0f;
}

// ---------------------------------------------------------------------------
// Kernel 2: dense levels 0..4 (combined tables ~4.1 MB, L2-resident)
// ---------------------------------------------------------------------------
__global__ __launch_bounds__(HTPB) void k_hash_dense(
    const float* __restrict__ g_tab,
    const float* __restrict__ xn0, const float* __restrict__ xn1,
    const float* __restrict__ xn2,
    float* __restrict__ featp, size_t stride, int N, int n_dense, LevelParams lp)
{
    const int n = blockIdx.x * HTPB + threadIdx.x;
    if (n >= N) return;
    const float xn[3] = { xn0[n], xn1[n], xn2[n] };

    for (int l = 0; l < n_dense; ++l) {
        const float scale = lp.scale[l];
        const int res = lp.res[l];
        float fr[3]; int c0[3];
#pragma unroll
        for (int d = 0; d < 3; ++d) {
            const float p = xn[d] * scale + 0.5f;
            const float fl = floorf(p);
            fr[d] = p - fl;
            c0[d] = (int)fl;
        }
        const float* __restrict__ tbl = g_tab + (size_t)l * (size_t)(TBL * 2);
        float2 v[8];
#pragma unroll
        for (int c = 0; c < 8; ++c) {
            const int ci = (c >> 2) & 1, cj = (c >> 1) & 1, ck = c & 1;
            const unsigned idx = (unsigned)((c0[0] + ci) + res * ((c0[1] + cj) + res * (c0[2] + ck)));
            v[c] = *reinterpret_cast<const float2*>(tbl + (size_t)idx * 2);
        }
        float f0 = 0.f, f1 = 0.f;
#pragma unroll
        for (int c = 0; c < 8; ++c) {
            const int ci = (c >> 2) & 1, cj = (c >> 1) & 1, ck = c & 1;
            const float w = (ci ? fr[0] : 1.f - fr[0])
                          * (cj ? fr[1] : 1.f - fr[1])
                          * (ck ? fr[2] : 1.f - fr[2]);
            f0 = fmaf(w, v[c].x, f0);
            f1 = fmaf(w, v[c].y, f1);
        }
        featp[(size_t)(2 * l)     * stride + n] = f0;
        featp[(size_t)(2 * l + 1) * stride + n] = f1;
    }
}

// ---------------------------------------------------------------------------
// Kernel 3 (x11): one hashed level; its 4 MB table becomes L2-resident per XCD
// ---------------------------------------------------------------------------
__global__ __launch_bounds__(HTPB) void k_hash_level(
    const float* __restrict__ tbl,
    const float* __restrict__ xn0, const float* __restrict__ xn1,
    const float* __restrict__ xn2,
    float* __restrict__ o0, float* __restrict__ o1, int N, float scale)
{
    const int n = blockIdx.x * HTPB + threadIdx.x;
    if (n >= N) return;
    const float xn[3] = { xn0[n], xn1[n], xn2[n] };

    float fr[3]; int c0[3];
#pragma unroll
    for (int d = 0; d < 3; ++d) {
        const float p = xn[d] * scale + 0.5f;
        const float fl = floorf(p);
        fr[d] = p - fl;
        c0[d] = (int)fl;
    }
    float2 v[8];
#pragma unroll
    for (int c = 0; c < 8; ++c) {
        const int ci = (c >> 2) & 1, cj = (c >> 1) & 1, ck = c & 1;
        const unsigned hx = (unsigned)(c0[0] + ci);
        const unsigned hy = (unsigned)(c0[1] + cj) * 2654435761u;
        const unsigned hz = (unsigned)(c0[2] + ck) * 805459861u;
        const unsigned idx = (hx ^ hy ^ hz) & (TBL - 1u);
        v[c] = *reinterpret_cast<const float2*>(tbl + (size_t)idx * 2);
    }
    float f0 = 0.f, f1 = 0.f;
#pragma unroll
    for (int c = 0; c < 8; ++c) {
        const int ci = (c >> 2) & 1, cj = (c >> 1) & 1, ck = c & 1;
        const float w = (ci ? fr[0] : 1.f - fr[0])
                      * (cj ? fr[1] : 1.f - fr[1])
                      * (ck ? fr[2] : 1.f - fr[2]);
        f0 = fmaf(w, v[c].x, f0);
        f1 = fmaf(w, v[c].y, f1);
    }
    o0[n] = f0;
    o1[n] = f1;
}

// ---------------------------------------------------------------------------
// Kernel 4: base MLP + SH + head MLP -> output
// ---------------------------------------------------------------------------
__global__ __launch_bounds__(TPB, 4) void k_final(
    const float* __restrict__ featp, size_t stride,
    const float* __restrict__ xn0, const float* __restrict__ xn1,
    const float* __restrict__ xn2,
    const float* __restrict__ g_dir,
    const float* __restrict__ Wb0, const float* __restrict__ Wb1,
    const float* __restrict__ Wh0, const float* __restrict__ Wh1,
    const float* __restrict__ Wh2,
    float* __restrict__ g_out, int N)
{
    __shared__ float s_act[CHUNK * TPB];
    const int tid = threadIdx.x;
    const int n = blockIdx.x * TPB + tid;
    if (n >= N) return;
    float* __restrict__ A = s_act + tid;

    float feat[32];
#pragma unroll
    for (int k = 0; k < 32; ++k) feat[k] = featp[(size_t)k * stride + n];

    float h[64], h2[64];
    layer<32, 64, false>(Wb0, feat, A, h);
    float b[16];
    layer<64, 16, true >(Wb1, h,    A, b);

    const float x0 = xn0[n], x1 = xn1[n], x2 = xn2[n];
    const bool sel = x0 > 0.f && x0 < 1.f && x1 > 0.f && x1 < 1.f && x2 > 0.f && x2 < 1.f;
    const float density = sel ? expf(b[0] - 1.0f) : 0.0f;

    float hin[31];
    {
        const float ddx = g_dir[3 * n + 0];
        const float ddy = g_dir[3 * n + 1];
        const float ddz = g_dir[3 * n + 2];
        const float nrm = sqrtf(ddx * ddx + ddy * ddy + ddz * ddz);
        const float x = ddx / nrm, y = ddy / nrm, z = ddz / nrm;
        const float xy = x * y, yz = y * z, xz = x * z;
        const float x2_ = x * x, y2 = y * y, z2 = z * z;
        hin[0]  = 0.28209479177387814f;
        hin[1]  = -0.48860251190291987f * y;
        hin[2]  = 0.48860251190291987f * z;
        hin[3]  = -0.48860251190291987f * x;
        hin[4]  = 1.0925484305920792f * xy;
        hin[5]  = -1.0925484305920792f * yz;
        hin[6]  = 0.94617469575756f * z2 - 0.31539156525252f;
        hin[7]  = -1.0925484305920792f * xz;
        hin[8]  = 0.5462742152960396f * (x2_ - y2);
        hin[9]  = 0.5900435899266435f * y * (y2 - 3.0f * x2_);
        hin[10] = 2.890611442640554f * xy * z;
        hin[11] = 0.4570457994644657f * y * (1.0f - 5.0f * z2);
        hin[12] = 0.3731763325901154f * z * (5.0f * z2 - 3.0f);
        hin[13] = 0.4570457994644657f * x * (1.0f - 5.0f * z2);
        hin[14] = 1.445305721320277f * z * (x2_ - y2);
        hin[15] = 0.5900435899266435f * x * (3.0f * y2 - x2_);
#pragma unroll
        for (int j = 0; j < 15; ++j) hin[16 + j] = b[1 + j];
    }

    layer<31, 64, false>(Wh0, hin, A, h);
    layer<64, 64, true >(Wh1, h,   A, h2);
    float rgb[3];
    layer<64, 3,  true >(Wh2, h2,  A, rgb);

    float4 o;
    o.x = 1.0f / (1.0f + expf(-rgb[0]));
    o.y = 1.0f / (1.0f + expf(-rgb[1]));
    o.z = 1.0f / (1.0f + expf(-rgb[2]));
    o.w = density;
    *reinterpret_cast<float4*>(g_out + (size_t)n * 4) = o;
}

// ---------------------------------------------------------------------------
// Fallback: round-2 monolithic kernel (used only if ws is too small)
// ---------------------------------------------------------------------------
__global__ __launch_bounds__(TPB, 4) void dngp_mono(
    const float* __restrict__ g_pos, const float* __restrict__ g_t,
    const float* __restrict__ g_dir, const float* __restrict__ g_tab,
    const float* __restrict__ Ww0, const float* __restrict__ Ww1, const float* __restrict__ Ww2,
    const float* __restrict__ Wb0, const float* __restrict__ Wb1,
    const float* __restrict__ Wh0, const float* __restrict__ Wh1, const float* __restrict__ Wh2,
    float* __restrict__ g_out, int N, LevelParams lp)
{
    __shared__ float s_act[CHUNK * TPB];
    const int tid = threadIdx.x;
    const int n = blockIdx.x * TPB + tid;
    if (n >= N) return;
    float* __restrict__ A = s_act + tid;

    const float px = g_pos[3 * n + 0];
    const float py = g_pos[3 * n + 1];
    const float pz = g_pos[3 * n + 2];
    const float tt = g_t[n];

    float enc[32];
    {
        const float xin[4] = { px, py, pz, tt };
        const float PI_F = 3.14159265358979323846f;
#pragma unroll
        for (int d = 0; d < 4; ++d)
#pragma unroll
            for (int k = 0; k < 4; ++k) {
                float s, c;
                sincosf(xin[d] * (PI_F * (float)(1 << k)), &s, &c);
                enc[d * 8 + k]     = s;
                enc[d * 8 + 4 + k] = c;
            }
    }

    float h[64], h2[64], off[3];
    layer<32, 64, false>(Ww0, enc, A, h);
    layer<64, 64, true >(Ww1, h,   A, h2);
    layer<64, 3,  true >(Ww2, h2,  A, off);

    const float xn[3] = { (px + off[0] * MOVE_STEP + 1.5f) / 3.0f,
                          (py + off[1] * MOVE_STEP + 1.5f) / 3.0f,
                          (pz + off[2] * MOVE_STEP + 1.5f) / 3.0f };
    const bool sel = xn[0] > 0.f && xn[0] < 1.f && xn[1] > 0.f && xn[1] < 1.f &&
                     xn[2] > 0.f && xn[2] < 1.f;

    float feat[32];
#pragma unroll 2
    for (int l = 0; l < N_LVL; ++l) {
        const float scale = lp.scale[l];
        const int res = lp.res[l];
        float fr[3]; int c0[3];
#pragma unroll
        for (int d = 0; d < 3; ++d) {
            const float p = xn[d] * scale + 0.5f;
            const float fl = floorf(p);
            fr[d] = p - fl;
            c0[d] = (int)fl;
        }
        const float* __restrict__ tbl = g_tab + (size_t)l * (size_t)(TBL * 2);
        float f0 = 0.f, f1 = 0.f;
        if (lp.dense[l]) {
#pragma unroll
            for (int c = 0; c < 8; ++c) {
                const int ci = (c >> 2) & 1, cj = (c >> 1) & 1, ck = c & 1;
                const unsigned idx = (unsigned)((c0[0] + ci) + res * ((c0[1] + cj) + res * (c0[2] + ck)));
                const float2 f = *reinterpret_cast<const float2*>(tbl + (size_t)idx * 2);
                const float w = (ci ? fr[0] : 1.f - fr[0]) * (cj ? fr[1] : 1.f - fr[1]) * (ck ? fr[2] : 1.f - fr[2]);
                f0 = fmaf(w, f.x, f0);
                f1 = fmaf(w, f.y, f1);
            }
        } else {
#pragma unroll
            for (int c = 0; c < 8; ++c) {
                const int ci = (c >> 2) & 1, cj = (c >> 1) & 1, ck = c & 1;
                const unsigned hx = (unsigned)(c0[0] + ci);
                const unsigned hy = (unsigned)(c0[1] + cj) * 2654435761u;
                const unsigned hz = (unsigned)(c0[2] + ck) * 805459861u;
                const unsigned idx = (hx ^ hy ^ hz) & (TBL - 1u);
                const float2 f = *reinterpret_cast<const float2*>(tbl + (size_t)idx * 2);
                const float w = (ci ? fr[0] : 1.f - fr[0]) * (cj ? fr[1] : 1.f - fr[1]) * (ck ? fr[2] : 1.f - fr[2]);
                f0 = fmaf(w, f.x, f0);
                f1 = fmaf(w, f.y, f1);
            }
        }
        feat[2 * l]     = f0;
        feat[2 * l + 1] = f1;
    }

    layer<32, 64, false>(Wb0, feat, A, h);
    float b[16];
    layer<64, 16, true >(Wb1, h, A, b);
    const float density = sel ? expf(b[0] - 1.0f) : 0.0f;

    float hin[31];
    {
        const float ddx = g_dir[3 * n + 0];
        const float ddy = g_dir[3 * n + 1];
        const float ddz = g_dir[3 * n + 2];
        const float nrm = sqrtf(ddx * ddx + ddy * ddy + ddz * ddz);
        const float x = ddx / nrm, y = ddy / nrm, z = ddz / nrm;
        const float xy = x * y, yz = y * z, xz = x * z;
        const float x2_ = x * x, y2 = y * y, z2 = z * z;
        hin[0]  = 0.28209479177387814f;
        hin[1]  = -0.48860251190291987f * y;
        hin[2]  = 0.48860251190291987f * z;
        hin[3]  = -0.48860251190291987f * x;
        hin[4]  = 1.0925484305920792f * xy;
        hin[5]  = -1.0925484305920792f * yz;
        hin[6]  = 0.94617469575756f * z2 - 0.31539156525252f;
        hin[7]  = -1.0925484305920792f * xz;
        hin[8]  = 0.5462742152960396f * (x2_ - y2);
        hin[9]  = 0.5900435899266435f * y * (y2 - 3.0f * x2_);
        hin[10] = 2.890611442640554f * xy * z;
        hin[11] = 0.4570457994644657f * y * (1.0f - 5.0f * z2);
        hin[12] = 0.3731763325901154f * z * (5.0f * z2 - 3.0f);
        hin[13] = 0.4570457994644657f * x * (1.0f - 5.0f * z2);
        hin[14] = 1.445305721320277f * z * (x2_ - y2);
        hin[15] = 0.5900435899266435f * x * (3.0f * y2 - x2_);
#pragma unroll
        for (int j = 0; j < 15; ++j) hin[16 + j] = b[1 + j];
    }

    layer<31, 64, false>(Wh0, hin, A, h);
    layer<64, 64, true >(Wh1, h,   A, h2);
    float rgb[3];
    layer<64, 3,  true >(Wh2, h2,  A, rgb);

    float4 o;
    o.x = 1.0f / (1.0f + expf(-rgb[0]));
    o.y = 1.0f / (1.0f + expf(-rgb[1]));
    o.z = 1.0f / (1.0f + expf(-rgb[2]));
    o.w = density;
    *reinterpret_cast<float4*>(g_out + (size_t)n * 4) = o;
}

extern "C" void kernel_launch(void* const* d_in, const int* in_sizes, int n_in,
                              void* d_out, int out_size, void* d_ws, size_t ws_size,
                              hipStream_t stream)
{
    const float* g_pos = (const float*)d_in[0];
    const float* g_t   = (const float*)d_in[1];
    const float* g_dir = (const float*)d_in[2];
    const float* g_tab = (const float*)d_in[3];
    const float* Ww0   = (const float*)d_in[4];
    const float* Ww1   = (const float*)d_in[5];
    const float* Ww2   = (const float*)d_in[6];
    const float* Wb0   = (const float*)d_in[7];
    const float* Wb1   = (const float*)d_in[8];
    const float* Wh0   = (const float*)d_in[9];
    const float* Wh1   = (const float*)d_in[10];
    const float* Wh2   = (const float*)d_in[11];
    const int N = in_sizes[0] / 3;

    LevelParams lp;
    int n_dense = 0;
    const double Bv = exp(log(4096.0 / 16.0) / 15.0);
    for (int l = 0; l < N_LVL; ++l) {
        const double s = 16.0 * pow(Bv, (double)l) - 1.0;
        lp.scale[l] = (float)s;
        const int r = (int)ceil(s) + 1;
        lp.res[l] = r;
        lp.dense[l] = ((long long)r * r * r <= (long long)TBL) ? 1 : 0;
        if (lp.dense[l]) n_dense = l + 1;
    }

    const size_t stride = (size_t)N + 256;          // pad to break L2 set aliasing
    const size_t ws_need = 35 * stride * sizeof(float);

    if (ws_size >= ws_need) {
        float* xn0   = (float*)d_ws;
        float* xn1   = xn0 + stride;
        float* xn2   = xn1 + stride;
        float* featp = xn2 + stride;                // 32 planes

        dim3 mgrid((N + TPB - 1) / TPB), mblock(TPB);
        dim3 hgrid((N + HTPB - 1) / HTPB), hblock(HTPB);

        hipLaunchKernelGGL(k_warp, mgrid, mblock, 0, stream,
                           g_pos, g_t, Ww0, Ww1, Ww2, xn0, xn1, xn2, N);

        hipLaunchKernelGGL(k_hash_dense, hgrid, hblock, 0, stream,
                           g_tab, xn0, xn1, xn2, featp, stride, N, n_dense, lp);

        for (int l = n_dense; l < N_LVL; ++l) {
            hipLaunchKernelGGL(k_hash_level, hgrid, hblock, 0, stream,
                               g_tab + (size_t)l * (size_t)(TBL * 2),
                               xn0, xn1, xn2,
                               featp + (size_t)(2 * l)     * stride,
                               featp + (size_t)(2 * l + 1) * stride,
                               N, lp.scale[l]);
        }

        hipLaunchKernelGGL(k_final, mgrid, mblock, 0, stream,
                           featp, stride, xn0, xn1, xn2, g_dir,
                           Wb0, Wb1, Wh0, Wh1, Wh2, (float*)d_out, N);
    } else {
        dim3 grid((N + TPB - 1) / TPB), block(TPB);
        hipLaunchKernelGGL(dngp_mono, grid, block, 0, stream,
                           g_pos, g_t, g_dir, g_tab,
                           Ww0, Ww1, Ww2, Wb0, Wb1, Wh0, Wh1, Wh2,
                           (float*)d_out, N, lp);
    }
}

// Round 4
// 425.573 us; speedup vs baseline: 1.5386x; 1.2745x over previous
//
#include <hip/hip_runtime.h>
#include <math.h>

#define TPB   128     // scalar MLP kernels (fallback)
#define HTPB  256     // hash kernels
#define CHUNK 32
#define LDW   68      // padded LDS row (f32): %4==0 for b128 align, breaks 32-bank stride
constexpr int  N_LVL = 16;
constexpr unsigned TBL = 1u << 19;
constexpr float MOVE_STEP = 1.0f / 4096.0f;

typedef __attribute__((ext_vector_type(8))) short short8;
typedef __attribute__((ext_vector_type(4))) float f32x4;

struct LevelParams { float scale[N_LVL]; int res[N_LVL]; int dense[N_LVL]; };

// ---- weight-fragment chunk bases (each chunk = 2048 B = hi[64][8] + lo[64][8] bf16)
enum { C_W0 = 0, C_W1 = 4, C_W2 = 12, C_B0 = 14, C_B1 = 18, C_H0 = 20, C_H1 = 24, C_H2 = 32, C_TOT = 34 };

struct LayerDesc { const float* W; int K; int N; int ksteps; int ntiles; int cbase; };
struct AllLayers { LayerDesc L[8]; };

__device__ __forceinline__ unsigned short f2bf(float x) {
    unsigned int u = __float_as_uint(x);
    u += 0x7FFFu + ((u >> 16) & 1u);            // RNE
    return (unsigned short)(u >> 16);
}
__device__ __forceinline__ float bf2f(unsigned short h) {
    return __uint_as_float(((unsigned int)h) << 16);
}

// ---------------------------------------------------------------------------
// prep: split weights into bf16 (hi,lo) MFMA B-fragments, per-lane order
// B-frag for 16x16x32: k = 8*(lane>>4)+j (+32*s), n = 16*t + (lane&15)
// ---------------------------------------------------------------------------
__global__ __launch_bounds__(256) void k_prep(AllLayers al, unsigned short* __restrict__ wfrag)
{
    const LayerDesc d = al.L[blockIdx.x];
    const int total = d.ksteps * d.ntiles * 64;
    for (int slot = threadIdx.x; slot < total; slot += 256) {
        const int lane = slot & 63;
        const int c = slot >> 6;
        const int s = c / d.ntiles;
        const int t = c - s * d.ntiles;
        short8 hv, lv;
#pragma unroll
        for (int j = 0; j < 8; ++j) {
            const int k = s * 32 + ((lane >> 4) << 3) + j;
            const int n = t * 16 + (lane & 15);
            const float w = (k < d.K && n < d.N) ? d.W[k * d.N + n] : 0.f;
            const unsigned short hi = f2bf(w);
            const unsigned short lo = f2bf(w - bf2f(hi));
            hv[j] = (short)hi;
            lv[j] = (short)lo;
        }
        short8* b8 = reinterpret_cast<short8*>(wfrag + (size_t)(d.cbase + c) * 1024);
        b8[lane]      = hv;
        b8[64 + lane] = lv;
    }
}

// ---------------------------------------------------------------------------
// wave-level dense layer via split-bf16 MFMA (3 terms: hh + lh + hl)
// Each wave computes 32 rows (2 M-subtiles of 16). No cross-wave data.
// ---------------------------------------------------------------------------
template<int KSTEPS, int NTILES, bool RELU>
__device__ __forceinline__ void wave_layer(const float* __restrict__ Xin,
                                           float* __restrict__ Xout,
                                           const unsigned short* __restrict__ wfrag, int cbase,
                                           int wrow, int lane)
{
    f32x4 acc[2][NTILES];
#pragma unroll
    for (int ms = 0; ms < 2; ++ms)
#pragma unroll
        for (int t = 0; t < NTILES; ++t) acc[ms][t] = f32x4{0.f, 0.f, 0.f, 0.f};
    const int r15 = lane & 15, q = lane >> 4;
    const short8* wf8 = reinterpret_cast<const short8*>(wfrag) + (size_t)cbase * 128;
#pragma unroll
    for (int s = 0; s < KSTEPS; ++s) {
        short8 ah[2], al[2];
#pragma unroll
        for (int ms = 0; ms < 2; ++ms) {
            const float* xp = Xin + (size_t)(wrow + ms * 16 + r15) * LDW + s * 32 + q * 8;
            const f32x4 x0 = reinterpret_cast<const f32x4*>(xp)[0];
            const f32x4 x1 = reinterpret_cast<const f32x4*>(xp)[1];
#pragma unroll
            for (int j = 0; j < 8; ++j) {
                const float x = (j < 4) ? x0[j] : x1[j - 4];
                const unsigned short hb = f2bf(x);
                const unsigned short lb = f2bf(x - bf2f(hb));
                ah[ms][j] = (short)hb;
                al[ms][j] = (short)lb;
            }
        }
#pragma unroll
        for (int t = 0; t < NTILES; ++t) {
            const short8* cp = wf8 + (size_t)(s * NTILES + t) * 128;
            const short8 bh = cp[lane];
            const short8 bl = cp[64 + lane];
#pragma unroll
            for (int ms = 0; ms < 2; ++ms) {
                acc[ms][t] = __builtin_amdgcn_mfma_f32_16x16x32_bf16(ah[ms], bh, acc[ms][t], 0, 0, 0);
                acc[ms][t] = __builtin_amdgcn_mfma_f32_16x16x32_bf16(al[ms], bh, acc[ms][t], 0, 0, 0);
                acc[ms][t] = __builtin_amdgcn_mfma_f32_16x16x32_bf16(ah[ms], bl, acc[ms][t], 0, 0, 0);
            }
        }
    }
    // D: row = 4*(lane>>4)+reg, col = lane&15
#pragma unroll
    for (int ms = 0; ms < 2; ++ms)
#pragma unroll
        for (int t = 0; t < NTILES; ++t)
#pragma unroll
            for (int r = 0; r < 4; ++r) {
                float v = acc[ms][t][r];
                if (RELU) v = fmaxf(v, 0.f);
                Xout[(size_t)(wrow + ms * 16 + q * 4 + r) * LDW + t * 16 + r15] = v;
            }
}

// ---------------------------------------------------------------------------
// Kernel 1: freq encode + warp MLP (MFMA) -> xn planes
// ---------------------------------------------------------------------------
__global__ __launch_bounds__(256, 2) void k_warp_mfma(
    const float* __restrict__ g_pos, const float* __restrict__ g_t,
    const unsigned short* __restrict__ wfrag,
    float* __restrict__ xn0, float* __restrict__ xn1, float* __restrict__ xn2, int N)
{
    __shared__ float bufA[128 * LDW];
    __shared__ float bufB[128 * LDW];
    const int tid = threadIdx.x;
    const int base = blockIdx.x * 128;
    const int p = tid & 127;
    const int pn = min(base + p, N - 1);
    const float PI_F = 3.14159265358979323846f;

    {   // enc staging: thread-pairs split the 4 input dims
        const int dpair = tid >> 7;
        float v0, v1;
        if (dpair == 0) { v0 = g_pos[3 * pn + 0]; v1 = g_pos[3 * pn + 1]; }
        else            { v0 = g_pos[3 * pn + 2]; v1 = g_t[pn]; }
#pragma unroll
        for (int e = 0; e < 2; ++e) {
            const float x = e ? v1 : v0;
            const int d = dpair * 2 + e;
            f32x4 sv, cv;
#pragma unroll
            for (int k = 0; k < 4; ++k) {
                const float a = x * (PI_F * (float)(1 << k));
                sv[k] = __sinf(a);
                cv[k] = __cosf(a);
            }
            *reinterpret_cast<f32x4*>(&bufA[(size_t)p * LDW + d * 8])     = sv;
            *reinterpret_cast<f32x4*>(&bufA[(size_t)p * LDW + d * 8 + 4]) = cv;
        }
    }
    __syncthreads();
    const int lane = tid & 63, wrow = (tid >> 6) * 32;
    wave_layer<1, 4, true >(bufA, bufB, wfrag, C_W0, wrow, lane);
    wave_layer<2, 4, true >(bufB, bufA, wfrag, C_W1, wrow, lane);
    wave_layer<2, 1, false>(bufA, bufB, wfrag, C_W2, wrow, lane);
    __syncthreads();
    if (tid < 128 && base + tid < N) {
        const int n = base + tid;
        const float ox = bufB[(size_t)tid * LDW + 0];
        const float oy = bufB[(size_t)tid * LDW + 1];
        const float oz = bufB[(size_t)tid * LDW + 2];
        xn0[n] = (g_pos[3 * n + 0] + ox * MOVE_STEP + 1.5f) / 3.0f;
        xn1[n] = (g_pos[3 * n + 1] + oy * MOVE_STEP + 1.5f) / 3.0f;
        xn2[n] = (g_pos[3 * n + 2] + oz * MOVE_STEP + 1.5f) / 3.0f;
    }
}

// ---------------------------------------------------------------------------
// Kernel 2: dense levels 0..n_dense-1 (used entries ~3.3 MB, L2-resident)
// ---------------------------------------------------------------------------
__global__ __launch_bounds__(HTPB) void k_hash_dense(
    const float* __restrict__ g_tab,
    const float* __restrict__ xn0, const float* __restrict__ xn1,
    const float* __restrict__ xn2,
    float* __restrict__ featp, size_t stride, int N, int n_dense, LevelParams lp)
{
    const int n = blockIdx.x * HTPB + threadIdx.x;
    if (n >= N) return;
    const float xn[3] = { xn0[n], xn1[n], xn2[n] };

    for (int l = 0; l < n_dense; ++l) {
        const float scale = lp.scale[l];
        const int res = lp.res[l];
        float fr[3]; int c0[3];
#pragma unroll
        for (int d = 0; d < 3; ++d) {
            const float pp = xn[d] * scale + 0.5f;
            const float fl = floorf(pp);
            fr[d] = pp - fl;
            c0[d] = (int)fl;
        }
        const float* __restrict__ tbl = g_tab + (size_t)l * (size_t)(TBL * 2);
        float2 v[8];
#pragma unroll
        for (int c = 0; c < 8; ++c) {
            const int ci = (c >> 2) & 1, cj = (c >> 1) & 1, ck = c & 1;
            const unsigned idx = (unsigned)((c0[0] + ci) + res * ((c0[1] + cj) + res * (c0[2] + ck)));
            v[c] = *reinterpret_cast<const float2*>(tbl + (size_t)idx * 2);
        }
        float f0 = 0.f, f1 = 0.f;
#pragma unroll
        for (int c = 0; c < 8; ++c) {
            const int ci = (c >> 2) & 1, cj = (c >> 1) & 1, ck = c & 1;
            const float w = (ci ? fr[0] : 1.f - fr[0])
                          * (cj ? fr[1] : 1.f - fr[1])
                          * (ck ? fr[2] : 1.f - fr[2]);
            f0 = fmaf(w, v[c].x, f0);
            f1 = fmaf(w, v[c].y, f1);
        }
        featp[(size_t)(2 * l)     * stride + n] = f0;
        featp[(size_t)(2 * l + 1) * stride + n] = f1;
    }
}

// ---------------------------------------------------------------------------
// Kernel 3 (x11): one hashed level per launch -> table L2-resident per XCD
// ---------------------------------------------------------------------------
__global__ __launch_bounds__(HTPB) void k_hash_level(
    const float* __restrict__ tbl,
    const float* __restrict__ xn0, const float* __restrict__ xn1,
    const float* __restrict__ xn2,
    float* __restrict__ o0, float* __restrict__ o1, int N, float scale)
{
    const int n = blockIdx.x * HTPB + threadIdx.x;
    if (n >= N) return;
    const float xn[3] = { xn0[n], xn1[n], xn2[n] };

    float fr[3]; int c0[3];
#pragma unroll
    for (int d = 0; d < 3; ++d) {
        const float pp = xn[d] * scale + 0.5f;
        const float fl = floorf(pp);
        fr[d] = pp - fl;
        c0[d] = (int)fl;
    }
    float2 v[8];
#pragma unroll
    for (int c = 0; c < 8; ++c) {
        const int ci = (c >> 2) & 1, cj = (c >> 1) & 1, ck = c & 1;
        const unsigned hx = (unsigned)(c0[0] + ci);
        const unsigned hy = (unsigned)(c0[1] + cj) * 2654435761u;
        const unsigned hz = (unsigned)(c0[2] + ck) * 805459861u;
        const unsigned idx = (hx ^ hy ^ hz) & (TBL - 1u);
        v[c] = *reinterpret_cast<const float2*>(tbl + (size_t)idx * 2);
    }
    float f0 = 0.f, f1 = 0.f;
#pragma unroll
    for (int c = 0; c < 8; ++c) {
        const int ci = (c >> 2) & 1, cj = (c >> 1) & 1, ck = c & 1;
        const float w = (ci ? fr[0] : 1.f - fr[0])
                      * (cj ? fr[1] : 1.f - fr[1])
                      * (ck ? fr[2] : 1.f - fr[2]);
        f0 = fmaf(w, v[c].x, f0);
        f1 = fmaf(w, v[c].y, f1);
    }
    o0[n] = f0;
    o1[n] = f1;
}

// ---------------------------------------------------------------------------
// Kernel 4: base MLP + SH + head MLP (MFMA) -> output
// ---------------------------------------------------------------------------
__global__ __launch_bounds__(256, 2) void k_final_mfma(
    const float* __restrict__ featp, size_t stride,
    const float* __restrict__ xn0, const float* __restrict__ xn1,
    const float* __restrict__ xn2,
    const float* __restrict__ g_dir,
    const unsigned short* __restrict__ wfrag,
    float* __restrict__ g_out, int N)
{
    __shared__ float bufA[128 * LDW];
    __shared__ float bufB[128 * LDW];
    const int tid = threadIdx.x;
    const int base = blockIdx.x * 128;
    const int p = tid & 127;
    const int pn = min(base + p, N - 1);
    const int fb = (tid >> 7) * 16;

    // stage 32 feat planes -> bufA[p][0..31]
#pragma unroll
    for (int j = 0; j < 16; ++j)
        bufA[(size_t)p * LDW + fb + j] = featp[(size_t)(fb + j) * stride + pn];
    __syncthreads();

    const int lane = tid & 63, wrow = (tid >> 6) * 32;
    wave_layer<1, 4, true >(bufA, bufB, wfrag, C_B0, wrow, lane);
    wave_layer<2, 1, false>(bufB, bufA, wfrag, C_B1, wrow, lane);
    __syncthreads();

    float density = 0.f;
    if (tid < 128) {
        float bb[16];
        const f32x4* bv = reinterpret_cast<const f32x4*>(&bufA[(size_t)tid * LDW]);
#pragma unroll
        for (int g4 = 0; g4 < 4; ++g4) {
            const f32x4 v = bv[g4];
#pragma unroll
            for (int j = 0; j < 4; ++j) bb[4 * g4 + j] = v[j];
        }
        const float x0v = xn0[pn], x1v = xn1[pn], x2v = xn2[pn];
        const bool sel = x0v > 0.f && x0v < 1.f && x1v > 0.f && x1v < 1.f &&
                         x2v > 0.f && x2v < 1.f;
        density = sel ? expf(bb[0] - 1.0f) : 0.0f;

        const float ddx = g_dir[3 * pn + 0];
        const float ddy = g_dir[3 * pn + 1];
        const float ddz = g_dir[3 * pn + 2];
        const float nrm = sqrtf(ddx * ddx + ddy * ddy + ddz * ddz);
        const float x = ddx / nrm, y = ddy / nrm, z = ddz / nrm;
        const float xy = x * y, yz = y * z, xz = x * z;
        const float x2 = x * x, y2 = y * y, z2 = z * z;
        f32x4 o0, o1, o2, o3, o4, o5, o6, o7;
        o0[0] = 0.28209479177387814f;
        o0[1] = -0.48860251190291987f * y;
        o0[2] = 0.48860251190291987f * z;
        o0[3] = -0.48860251190291987f * x;
        o1[0] = 1.0925484305920792f * xy;
        o1[1] = -1.0925484305920792f * yz;
        o1[2] = 0.94617469575756f * z2 - 0.31539156525252f;
        o1[3] = -1.0925484305920792f * xz;
        o2[0] = 0.5462742152960396f * (x2 - y2);
        o2[1] = 0.5900435899266435f * y * (y2 - 3.0f * x2);
        o2[2] = 2.890611442640554f * xy * z;
        o2[3] = 0.4570457994644657f * y * (1.0f - 5.0f * z2);
        o3[0] = 0.3731763325901154f * z * (5.0f * z2 - 3.0f);
        o3[1] = 0.4570457994644657f * x * (1.0f - 5.0f * z2);
        o3[2] = 1.445305721320277f * z * (x2 - y2);
        o3[3] = 0.5900435899266435f * x * (3.0f * y2 - x2);
        o4[0] = bb[1];  o4[1] = bb[2];  o4[2] = bb[3];  o4[3] = bb[4];
        o5[0] = bb[5];  o5[1] = bb[6];  o5[2] = bb[7];  o5[3] = bb[8];
        o6[0] = bb[9];  o6[1] = bb[10]; o6[2] = bb[11]; o6[3] = bb[12];
        o7[0] = bb[13]; o7[1] = bb[14]; o7[2] = bb[15]; o7[3] = 0.f;
        f32x4* wb = reinterpret_cast<f32x4*>(&bufB[(size_t)tid * LDW]);
        wb[0] = o0; wb[1] = o1; wb[2] = o2; wb[3] = o3;
        wb[4] = o4; wb[5] = o5; wb[6] = o6; wb[7] = o7;
    }
    __syncthreads();

    wave_layer<1, 4, true >(bufB, bufA, wfrag, C_H0, wrow, lane);
    wave_layer<2, 4, true >(bufA, bufB, wfrag, C_H1, wrow, lane);
    wave_layer<2, 1, false>(bufB, bufA, wfrag, C_H2, wrow, lane);
    __syncthreads();

    if (tid < 128 && base + tid < N) {
        const int n = base + tid;
        float4 o;
        o.x = 1.0f / (1.0f + expf(-bufA[(size_t)tid * LDW + 0]));
        o.y = 1.0f / (1.0f + expf(-bufA[(size_t)tid * LDW + 1]));
        o.z = 1.0f / (1.0f + expf(-bufA[(size_t)tid * LDW + 2]));
        o.w = density;
        *reinterpret_cast<float4*>(g_out + (size_t)n * 4) = o;
    }
}

// ---------------------------------------------------------------------------
// Scalar fallback (round-2 monolith) used only if ws too small
// ---------------------------------------------------------------------------
template<int IN, int OUT, bool RELU>
__device__ __forceinline__ void layer(const float* __restrict__ W,
                                      const float* __restrict__ hin,
                                      float* __restrict__ A,
                                      float* __restrict__ out)
{
#pragma unroll
    for (int j = 0; j < OUT; ++j) out[j] = 0.f;
#pragma unroll
    for (int c = 0; c < IN; c += CHUNK) {
#pragma unroll
        for (int i = 0; i < CHUNK; ++i) {
            if (c + i < IN) A[i * TPB] = RELU ? fmaxf(hin[c + i], 0.f) : hin[c + i];
        }
        const int cnt = (IN - c < CHUNK) ? (IN - c) : CHUNK;
#pragma unroll 4
        for (int i = 0; i < cnt; ++i) {
            const float a = A[i * TPB];
            const float* __restrict__ Wr = W + (size_t)(c + i) * OUT;
#pragma unroll
            for (int j = 0; j < OUT; ++j)
                out[j] = fmaf(a, Wr[j], out[j]);
        }
    }
}

__global__ __launch_bounds__(TPB, 4) void dngp_mono(
    const float* __restrict__ g_pos, const float* __restrict__ g_t,
    const float* __restrict__ g_dir, const float* __restrict__ g_tab,
    const float* __restrict__ Ww0, const float* __restrict__ Ww1, const float* __restrict__ Ww2,
    const float* __restrict__ Wb0, const float* __restrict__ Wb1,
    const float* __restrict__ Wh0, const float* __restrict__ Wh1, const float* __restrict__ Wh2,
    float* __restrict__ g_out, int N, LevelParams lp)
{
    __shared__ float s_act[CHUNK * TPB];
    const int tid = threadIdx.x;
    const int n = blockIdx.x * TPB + tid;
    if (n >= N) return;
    float* __restrict__ A = s_act + tid;

    const float px = g_pos[3 * n + 0];
    const float py = g_pos[3 * n + 1];
    const float pz = g_pos[3 * n + 2];
    const float tt = g_t[n];

    float enc[32];
    {
        const float xin[4] = { px, py, pz, tt };
        const float PI_F = 3.14159265358979323846f;
#pragma unroll
        for (int d = 0; d < 4; ++d)
#pragma unroll
            for (int k = 0; k < 4; ++k) {
                float s, c;
                sincosf(xin[d] * (PI_F * (float)(1 << k)), &s, &c);
                enc[d * 8 + k]     = s;
                enc[d * 8 + 4 + k] = c;
            }
    }

    float h[64], h2[64], off[3];
    layer<32, 64, false>(Ww0, enc, A, h);
    layer<64, 64, true >(Ww1, h,   A, h2);
    layer<64, 3,  true >(Ww2, h2,  A, off);

    const float xn[3] = { (px + off[0] * MOVE_STEP + 1.5f) / 3.0f,
                          (py + off[1] * MOVE_STEP + 1.5f) / 3.0f,
                          (pz + off[2] * MOVE_STEP + 1.5f) / 3.0f };
    const bool sel = xn[0] > 0.f && xn[0] < 1.f && xn[1] > 0.f && xn[1] < 1.f &&
                     xn[2] > 0.f && xn[2] < 1.f;

    float feat[32];
#pragma unroll 2
    for (int l = 0; l < N_LVL; ++l) {
        const float scale = lp.scale[l];
        const int res = lp.res[l];
        float fr[3]; int c0[3];
#pragma unroll
        for (int d = 0; d < 3; ++d) {
            const float pp = xn[d] * scale + 0.5f;
            const float fl = floorf(pp);
            fr[d] = pp - fl;
            c0[d] = (int)fl;
        }
        const float* __restrict__ tbl = g_tab + (size_t)l * (size_t)(TBL * 2);
        float f0 = 0.f, f1 = 0.f;
        if (lp.dense[l]) {
#pragma unroll
            for (int c = 0; c < 8; ++c) {
                const int ci = (c >> 2) & 1, cj = (c >> 1) & 1, ck = c & 1;
                const unsigned idx = (unsigned)((c0[0] + ci) + res * ((c0[1] + cj) + res * (c0[2] + ck)));
                const float2 f = *reinterpret_cast<const float2*>(tbl + (size_t)idx * 2);
                const float w = (ci ? fr[0] : 1.f - fr[0]) * (cj ? fr[1] : 1.f - fr[1]) * (ck ? fr[2] : 1.f - fr[2]);
                f0 = fmaf(w, f.x, f0);
                f1 = fmaf(w, f.y, f1);
            }
        } else {
#pragma unroll
            for (int c = 0; c < 8; ++c) {
                const int ci = (c >> 2) & 1, cj = (c >> 1) & 1, ck = c & 1;
                const unsigned hx = (unsigned)(c0[0] + ci);
                const unsigned hy = (unsigned)(c0[1] + cj) * 2654435761u;
                const unsigned hz = (unsigned)(c0[2] + ck) * 805459861u;
                const unsigned idx = (hx ^ hy ^ hz) & (TBL - 1u);
                const float2 f = *reinterpret_cast<const float2*>(tbl + (size_t)idx * 2);
                const float w = (ci ? fr[0] : 1.f - fr[0]) * (cj ? fr[1] : 1.f - fr[1]) * (ck ? fr[2] : 1.f - fr[2]);
                f0 = fmaf(w, f.x, f0);
                f1 = fmaf(w, f.y, f1);
            }
        }
        feat[2 * l]     = f0;
        feat[2 * l + 1] = f1;
    }

    layer<32, 64, false>(Wb0, feat, A, h);
    float b[16];
    layer<64, 16, true >(Wb1, h, A, b);
    const float density = sel ? expf(b[0] - 1.0f) : 0.0f;

    float hin[31];
    {
        const float ddx = g_dir[3 * n + 0];
        const float ddy = g_dir[3 * n + 1];
        const float ddz = g_dir[3 * n + 2];
        const float nrm = sqrtf(ddx * ddx + ddy * ddy + ddz * ddz);
        const float x = ddx / nrm, y = ddy / nrm, z = ddz / nrm;
        const float xy = x * y, yz = y * z, xz = x * z;
        const float x2_ = x * x, y2 = y * y, z2 = z * z;
        hin[0]  = 0.28209479177387814f;
        hin[1]  = -0.48860251190291987f * y;
        hin[2]  = 0.48860251190291987f * z;
        hin[3]  = -0.48860251190291987f * x;
        hin[4]  = 1.0925484305920792f * xy;
        hin[5]  = -1.0925484305920792f * yz;
        hin[6]  = 0.94617469575756f * z2 - 0.31539156525252f;
        hin[7]  = -1.0925484305920792f * xz;
        hin[8]  = 0.5462742152960396f * (x2_ - y2);
        hin[9]  = 0.5900435899266435f * y * (y2 - 3.0f * x2_);
        hin[10] = 2.890611442640554f * xy * z;
        hin[11] = 0.4570457994644657f * y * (1.0f - 5.0f * z2);
        hin[12] = 0.3731763325901154f * z * (5.0f * z2 - 3.0f);
        hin[13] = 0.4570457994644657f * x * (1.0f - 5.0f * z2);
        hin[14] = 1.445305721320277f * z * (x2_ - y2);
        hin[15] = 0.5900435899266435f * x * (3.0f * y2 - x2_);
#pragma unroll
        for (int j = 0; j < 15; ++j) hin[16 + j] = b[1 + j];
    }

    layer<31, 64, false>(Wh0, hin, A, h);
    layer<64, 64, true >(Wh1, h,   A, h2);
    float rgb[3];
    layer<64, 3,  true >(Wh2, h2,  A, rgb);

    float4 o;
    o.x = 1.0f / (1.0f + expf(-rgb[0]));
    o.y = 1.0f / (1.0f + expf(-rgb[1]));
    o.z = 1.0f / (1.0f + expf(-rgb[2]));
    o.w = density;
    *reinterpret_cast<float4*>(g_out + (size_t)n * 4) = o;
}

extern "C" void kernel_launch(void* const* d_in, const int* in_sizes, int n_in,
                              void* d_out, int out_size, void* d_ws, size_t ws_size,
                              hipStream_t stream)
{
    const float* g_pos = (const float*)d_in[0];
    const float* g_t   = (const float*)d_in[1];
    const float* g_dir = (const float*)d_in[2];
    const float* g_tab = (const float*)d_in[3];
    const float* Ww0   = (const float*)d_in[4];
    const float* Ww1   = (const float*)d_in[5];
    const float* Ww2   = (const float*)d_in[6];
    const float* Wb0   = (const float*)d_in[7];
    const float* Wb1   = (const float*)d_in[8];
    const float* Wh0   = (const float*)d_in[9];
    const float* Wh1   = (const float*)d_in[10];
    const float* Wh2   = (const float*)d_in[11];
    const int N = in_sizes[0] / 3;

    LevelParams lp;
    int n_dense = 0;
    const double Bv = exp(log(4096.0 / 16.0) / 15.0);
    for (int l = 0; l < N_LVL; ++l) {
        const double s = 16.0 * pow(Bv, (double)l) - 1.0;
        lp.scale[l] = (float)s;
        const int r = (int)ceil(s) + 1;
        lp.res[l] = r;
        lp.dense[l] = ((long long)r * r * r <= (long long)TBL) ? 1 : 0;
        if (lp.dense[l]) n_dense = l + 1;
    }

    const size_t stride = ((size_t)N + 259) & ~(size_t)3;   // pad + keep 16B plane align
    const size_t ws_need = 35 * stride * sizeof(float) + (size_t)C_TOT * 2048;

    if (ws_size >= ws_need) {
        float* xn0   = (float*)d_ws;
        float* xn1   = xn0 + stride;
        float* xn2   = xn1 + stride;
        float* featp = xn2 + stride;                         // 32 planes
        unsigned short* wfrag = (unsigned short*)(featp + 32 * stride);

        AllLayers al;
        al.L[0] = { Ww0, 32, 64, 1, 4, C_W0 };
        al.L[1] = { Ww1, 64, 64, 2, 4, C_W1 };
        al.L[2] = { Ww2, 64,  3, 2, 1, C_W2 };
        al.L[3] = { Wb0, 32, 64, 1, 4, C_B0 };
        al.L[4] = { Wb1, 64, 16, 2, 1, C_B1 };
        al.L[5] = { Wh0, 31, 64, 1, 4, C_H0 };
        al.L[6] = { Wh1, 64, 64, 2, 4, C_H1 };
        al.L[7] = { Wh2, 64,  3, 2, 1, C_H2 };

        dim3 mgrid((N + 127) / 128), mblock(256);
        dim3 hgrid((N + HTPB - 1) / HTPB), hblock(HTPB);

        hipLaunchKernelGGL(k_prep, dim3(8), dim3(256), 0, stream, al, wfrag);

        hipLaunchKernelGGL(k_warp_mfma, mgrid, mblock, 0, stream,
                           g_pos, g_t, wfrag, xn0, xn1, xn2, N);

        hipLaunchKernelGGL(k_hash_dense, hgrid, hblock, 0, stream,
                           g_tab, xn0, xn1, xn2, featp, stride, N, n_dense, lp);

        for (int l = n_dense; l < N_LVL; ++l) {
            hipLaunchKernelGGL(k_hash_level, hgrid, hblock, 0, stream,
                               g_tab + (size_t)l * (size_t)(TBL * 2),
                               xn0, xn1, xn2,
                               featp + (size_t)(2 * l)     * stride,
                               featp + (size_t)(2 * l + 1) * stride,
                               N, lp.scale[l]);
        }

        hipLaunchKernelGGL(k_final_mfma, mgrid, mblock, 0, stream,
                           featp, stride, xn0, xn1, xn2, g_dir,
                           wfrag, (float*)d_out, N);
    } else {
        dim3 grid((N + TPB - 1) / TPB), block(TPB);
        hipLaunchKernelGGL(dngp_mono, grid, block, 0, stream,
                           g_pos, g_t, g_dir, g_tab,
                           Ww0, Ww1, Ww2, Wb0, Wb1, Wh0, Wh1, Wh2,
                           (float*)d_out, N, lp);
    }
}

// Round 7
// 392.560 us; speedup vs baseline: 1.6680x; 1.0841x over previous
//
#include <hip/hip_runtime.h>
#include <math.h>

#define TPB   128     // scalar fallback
#define HTPB  256
#define CHUNK 32
#define LDW   68      // f32 LDS row stride: 272 B, 16B-aligned
constexpr int  N_LVL = 16;
constexpr unsigned TBL = 1u << 19;
constexpr float MOVE_STEP = 1.0f / 4096.0f;

typedef __attribute__((ext_vector_type(8))) short short8;
typedef __attribute__((ext_vector_type(4))) float f32x4;

struct LevelParams { float scale[N_LVL]; int res[N_LVL]; int dense[N_LVL]; };

// weight-fragment chunks (2048 B each = hi[64 lanes][short8] + lo[...])
enum { C_W0 = 0, C_W1 = 4, C_W2 = 12, C_B0 = 14, C_B1 = 18, C_H0 = 20, C_H1 = 24, C_H2 = 32, C_TOT = 34 };

struct LayerDesc { const float* W; int K; int N; int ksteps; int ntiles; int cbase; };
struct AllLayers { LayerDesc L[8]; };

__device__ __forceinline__ unsigned short f2bf(float x) {
    unsigned int u = __float_as_uint(x);
    u += 0x7FFFu + ((u >> 16) & 1u);            // RNE
    return (unsigned short)(u >> 16);
}
__device__ __forceinline__ float bf2f(unsigned short h) {
    return __uint_as_float(((unsigned int)h) << 16);
}

// ---------------------------------------------------------------------------
// prep: split weights into bf16 (hi,lo) MFMA B-fragments (RNE), per-lane order
// (identical to R4's proven k_prep)
// ---------------------------------------------------------------------------
__global__ __launch_bounds__(256) void k_prep(AllLayers al, unsigned short* __restrict__ wfrag)
{
    const LayerDesc d = al.L[blockIdx.x];
    const int total = d.ksteps * d.ntiles * 64;
    for (int slot = threadIdx.x; slot < total; slot += 256) {
        const int lane = slot & 63;
        const int c = slot >> 6;
        const int s = c / d.ntiles;
        const int t = c - s * d.ntiles;
        short8 hv, lv;
#pragma unroll
        for (int j = 0; j < 8; ++j) {
            const int k = s * 32 + ((lane >> 4) << 3) + j;
            const int n = t * 16 + (lane & 15);
            const float w = (k < d.K && n < d.N) ? d.W[k * d.N + n] : 0.f;
            const unsigned short hi = f2bf(w);
            const unsigned short lo = f2bf(w - bf2f(hi));
            hv[j] = (short)hi;
            lv[j] = (short)lo;
        }
        short8* b8 = reinterpret_cast<short8*>(wfrag + (size_t)(d.cbase + c) * 1024);
        b8[lane]      = hv;
        b8[64 + lane] = lv;
    }
}

// ---------------------------------------------------------------------------
// wave dense layer, R4 numerics exactly: f32 LDS in, per-k-step RNE hi/lo
// split, 3-term MFMA (hh + lh + hl), f32 LDS out. IN-PLACE on one buffer:
// safe because every DS-write depends on all ds_reads of its own ms (acc
// chain), and cross-ms write/read row ranges are disjoint ([wrow,wrow+16) vs
// [wrow+16,wrow+32)); same-wave DS ops execute in order.
// ---------------------------------------------------------------------------
template<int KSTEPS, int NTILES, bool RELU>
__device__ __forceinline__ void wave_layer(float* X,
                                           const unsigned short* __restrict__ wfrag, int cbase,
                                           int wrow, int lane)
{
    f32x4 acc[2][NTILES];
#pragma unroll
    for (int ms = 0; ms < 2; ++ms)
#pragma unroll
        for (int t = 0; t < NTILES; ++t) acc[ms][t] = f32x4{0.f, 0.f, 0.f, 0.f};
    const int r15 = lane & 15, q = lane >> 4;
    const short8* wf8 = reinterpret_cast<const short8*>(wfrag) + (size_t)cbase * 128;
#pragma unroll
    for (int s = 0; s < KSTEPS; ++s) {
        short8 ah[2], al[2];
#pragma unroll
        for (int ms = 0; ms < 2; ++ms) {
            const float* xp = X + (size_t)(wrow + ms * 16 + r15) * LDW + s * 32 + q * 8;
            const f32x4 x0 = reinterpret_cast<const f32x4*>(xp)[0];
            const f32x4 x1 = reinterpret_cast<const f32x4*>(xp)[1];
#pragma unroll
            for (int j = 0; j < 8; ++j) {
                const float x = (j < 4) ? x0[j] : x1[j - 4];
                const unsigned short hb = f2bf(x);
                const unsigned short lb = f2bf(x - bf2f(hb));
                ah[ms][j] = (short)hb;
                al[ms][j] = (short)lb;
            }
        }
#pragma unroll
        for (int t = 0; t < NTILES; ++t) {
            const short8* cp = wf8 + (size_t)(s * NTILES + t) * 128;
            const short8 bh = cp[lane];
            const short8 bl = cp[64 + lane];
#pragma unroll
            for (int ms = 0; ms < 2; ++ms) {
                acc[ms][t] = __builtin_amdgcn_mfma_f32_16x16x32_bf16(ah[ms], bh, acc[ms][t], 0, 0, 0);
                acc[ms][t] = __builtin_amdgcn_mfma_f32_16x16x32_bf16(al[ms], bh, acc[ms][t], 0, 0, 0);
                acc[ms][t] = __builtin_amdgcn_mfma_f32_16x16x32_bf16(ah[ms], bl, acc[ms][t], 0, 0, 0);
            }
        }
    }
    // D: row = 4*(lane>>4)+reg, col = lane&15
#pragma unroll
    for (int ms = 0; ms < 2; ++ms)
#pragma unroll
        for (int t = 0; t < NTILES; ++t)
#pragma unroll
            for (int r = 0; r < 4; ++r) {
                float v = acc[ms][t][r];
                if (RELU) v = fmaxf(v, 0.f);
                X[(size_t)(wrow + ms * 16 + q * 4 + r) * LDW + t * 16 + r15] = v;
            }
}

// ---------------------------------------------------------------------------
// Kernel 1: freq encode + warp MLP (MFMA) -> xn planes
// ---------------------------------------------------------------------------
__global__ __launch_bounds__(256, 4) void k_warp_mfma(
    const float* __restrict__ g_pos, const float* __restrict__ g_t,
    const unsigned short* __restrict__ wfrag,
    float* __restrict__ xn0, float* __restrict__ xn1, float* __restrict__ xn2, int N)
{
    __shared__ float buf[128 * LDW];        // 34.8 KB
    const int tid = threadIdx.x;
    const int base = blockIdx.x * 128;
    const int p = tid & 127;
    const int pn = min(base + p, N - 1);
    const float PI_F = 3.14159265358979323846f;

    {   // enc staging: thread-pairs split the 4 input dims (f32, R4-identical)
        const int dpair = tid >> 7;
        float v0, v1;
        if (dpair == 0) { v0 = g_pos[3 * pn + 0]; v1 = g_pos[3 * pn + 1]; }
        else            { v0 = g_pos[3 * pn + 2]; v1 = g_t[pn]; }
#pragma unroll
        for (int e = 0; e < 2; ++e) {
            const float x = e ? v1 : v0;
            const int d = dpair * 2 + e;
            f32x4 sv, cv;
#pragma unroll
            for (int k = 0; k < 4; ++k) {
                const float a = x * (PI_F * (float)(1 << k));
                sv[k] = __sinf(a);
                cv[k] = __cosf(a);
            }
            *reinterpret_cast<f32x4*>(&buf[(size_t)p * LDW + d * 8])     = sv;
            *reinterpret_cast<f32x4*>(&buf[(size_t)p * LDW + d * 8 + 4]) = cv;
        }
    }
    __syncthreads();
    const int lane = tid & 63, wrow = (tid >> 6) * 32;
    wave_layer<1, 4, true >(buf, wfrag, C_W0, wrow, lane);
    wave_layer<2, 4, true >(buf, wfrag, C_W1, wrow, lane);
    wave_layer<2, 1, false>(buf, wfrag, C_W2, wrow, lane);
    __syncthreads();
    if (tid < 128 && base + tid < N) {
        const int n = base + tid;
        const float ox = buf[(size_t)tid * LDW + 0];
        const float oy = buf[(size_t)tid * LDW + 1];
        const float oz = buf[(size_t)tid * LDW + 2];
        xn0[n] = (g_pos[3 * n + 0] + ox * MOVE_STEP + 1.5f) / 3.0f;
        xn1[n] = (g_pos[3 * n + 1] + oy * MOVE_STEP + 1.5f) / 3.0f;
        xn2[n] = (g_pos[3 * n + 2] + oz * MOVE_STEP + 1.5f) / 3.0f;
    }
}

// ---------------------------------------------------------------------------
// Kernel 2: dense levels, 2 points/thread, f32 feat planes
// ---------------------------------------------------------------------------
__global__ __launch_bounds__(HTPB) void k_hash_dense(
    const float* __restrict__ g_tab,
    const float* __restrict__ xn0, const float* __restrict__ xn1,
    const float* __restrict__ xn2,
    float* __restrict__ featp, size_t stride, int N, int n_dense, LevelParams lp)
{
    const int n0 = blockIdx.x * (HTPB * 2) + threadIdx.x;
    const int n1 = n0 + HTPB;
    const bool a0 = n0 < N, a1 = n1 < N;
    const int m0 = a0 ? n0 : 0, m1 = a1 ? n1 : 0;
    const float xa[3] = { xn0[m0], xn1[m0], xn2[m0] };
    const float xb[3] = { xn0[m1], xn1[m1], xn2[m1] };

    for (int l = 0; l < n_dense; ++l) {
        const float scale = lp.scale[l];
        const int res = lp.res[l];
        float fra[3], frb[3]; int ca[3], cb[3];
#pragma unroll
        for (int d = 0; d < 3; ++d) {
            float pp = xa[d] * scale + 0.5f, fl = floorf(pp);
            fra[d] = pp - fl; ca[d] = (int)fl;
            pp = xb[d] * scale + 0.5f; fl = floorf(pp);
            frb[d] = pp - fl; cb[d] = (int)fl;
        }
        const float* __restrict__ tbl = g_tab + (size_t)l * (size_t)(TBL * 2);
        float2 va[8], vb[8];
#pragma unroll
        for (int c = 0; c < 8; ++c) {
            const int ci = (c >> 2) & 1, cj = (c >> 1) & 1, ck = c & 1;
            const unsigned ia = (unsigned)((ca[0] + ci) + res * ((ca[1] + cj) + res * (ca[2] + ck)));
            va[c] = *reinterpret_cast<const float2*>(tbl + (size_t)ia * 2);
        }
#pragma unroll
        for (int c = 0; c < 8; ++c) {
            const int ci = (c >> 2) & 1, cj = (c >> 1) & 1, ck = c & 1;
            const unsigned ib = (unsigned)((cb[0] + ci) + res * ((cb[1] + cj) + res * (cb[2] + ck)));
            vb[c] = *reinterpret_cast<const float2*>(tbl + (size_t)ib * 2);
        }
        float f0a = 0.f, f1a = 0.f, f0b = 0.f, f1b = 0.f;
#pragma unroll
        for (int c = 0; c < 8; ++c) {
            const int ci = (c >> 2) & 1, cj = (c >> 1) & 1, ck = c & 1;
            const float wa = (ci ? fra[0] : 1.f - fra[0]) * (cj ? fra[1] : 1.f - fra[1]) * (ck ? fra[2] : 1.f - fra[2]);
            const float wb = (ci ? frb[0] : 1.f - frb[0]) * (cj ? frb[1] : 1.f - frb[1]) * (ck ? frb[2] : 1.f - frb[2]);
            f0a = fmaf(wa, va[c].x, f0a); f1a = fmaf(wa, va[c].y, f1a);
            f0b = fmaf(wb, vb[c].x, f0b); f1b = fmaf(wb, vb[c].y, f1b);
        }
        if (a0) { featp[(size_t)(2 * l) * stride + n0] = f0a; featp[(size_t)(2 * l + 1) * stride + n0] = f1a; }
        if (a1) { featp[(size_t)(2 * l) * stride + n1] = f0b; featp[(size_t)(2 * l + 1) * stride + n1] = f1b; }
    }
}

// ---------------------------------------------------------------------------
// Kernel 3 (x11): one hashed level, 2 points/thread, f32 feat planes
// ---------------------------------------------------------------------------
__global__ __launch_bounds__(HTPB) void k_hash_level(
    const float* __restrict__ tbl,
    const float* __restrict__ xn0, const float* __restrict__ xn1,
    const float* __restrict__ xn2,
    float* __restrict__ o0, float* __restrict__ o1, int N, float scale)
{
    const int n0 = blockIdx.x * (HTPB * 2) + threadIdx.x;
    const int n1 = n0 + HTPB;
    const bool a0 = n0 < N, a1 = n1 < N;
    const int m0 = a0 ? n0 : 0, m1 = a1 ? n1 : 0;
    const float xa[3] = { xn0[m0], xn1[m0], xn2[m0] };
    const float xb[3] = { xn0[m1], xn1[m1], xn2[m1] };

    float fra[3], frb[3]; int ca[3], cb[3];
#pragma unroll
    for (int d = 0; d < 3; ++d) {
        float pp = xa[d] * scale + 0.5f, fl = floorf(pp);
        fra[d] = pp - fl; ca[d] = (int)fl;
        pp = xb[d] * scale + 0.5f; fl = floorf(pp);
        frb[d] = pp - fl; cb[d] = (int)fl;
    }
    float2 va[8], vb[8];
#pragma unroll
    for (int c = 0; c < 8; ++c) {
        const int ci = (c >> 2) & 1, cj = (c >> 1) & 1, ck = c & 1;
        const unsigned ia = (((unsigned)(ca[0] + ci)) ^ ((unsigned)(ca[1] + cj) * 2654435761u)
                             ^ ((unsigned)(ca[2] + ck) * 805459861u)) & (TBL - 1u);
        va[c] = *reinterpret_cast<const float2*>(tbl + (size_t)ia * 2);
    }
#pragma unroll
    for (int c = 0; c < 8; ++c) {
        const int ci = (c >> 2) & 1, cj = (c >> 1) & 1, ck = c & 1;
        const unsigned ib = (((unsigned)(cb[0] + ci)) ^ ((unsigned)(cb[1] + cj) * 2654435761u)
                             ^ ((unsigned)(cb[2] + ck) * 805459861u)) & (TBL - 1u);
        vb[c] = *reinterpret_cast<const float2*>(tbl + (size_t)ib * 2);
    }
    float f0a = 0.f, f1a = 0.f, f0b = 0.f, f1b = 0.f;
#pragma unroll
    for (int c = 0; c < 8; ++c) {
        const int ci = (c >> 2) & 1, cj = (c >> 1) & 1, ck = c & 1;
        const float wa = (ci ? fra[0] : 1.f - fra[0]) * (cj ? fra[1] : 1.f - fra[1]) * (ck ? fra[2] : 1.f - fra[2]);
        const float wb = (ci ? frb[0] : 1.f - frb[0]) * (cj ? frb[1] : 1.f - frb[1]) * (ck ? frb[2] : 1.f - frb[2]);
        f0a = fmaf(wa, va[c].x, f0a); f1a = fmaf(wa, va[c].y, f1a);
        f0b = fmaf(wb, vb[c].x, f0b); f1b = fmaf(wb, vb[c].y, f1b);
    }
    if (a0) { o0[n0] = f0a; o1[n0] = f1a; }
    if (a1) { o0[n1] = f0b; o1[n1] = f1b; }
}

// ---------------------------------------------------------------------------
// Kernel 4: base MLP + SH + head MLP (MFMA) -> output
// ---------------------------------------------------------------------------
__global__ __launch_bounds__(256, 4) void k_final_mfma(
    const float* __restrict__ featp, size_t stride,
    const float* __restrict__ xn0, const float* __restrict__ xn1,
    const float* __restrict__ xn2,
    const float* __restrict__ g_dir,
    const unsigned short* __restrict__ wfrag,
    float* __restrict__ g_out, int N)
{
    __shared__ float buf[128 * LDW];        // 34.8 KB
    const int tid = threadIdx.x;
    const int base = blockIdx.x * 128;
    const int p = tid & 127;
    const int pn = min(base + p, N - 1);
    const int fb = (tid >> 7) * 16;

    // stage 32 f32 feat planes -> buf[p][0..31]
#pragma unroll
    for (int j = 0; j < 16; ++j)
        buf[(size_t)p * LDW + fb + j] = featp[(size_t)(fb + j) * stride + pn];
    __syncthreads();

    const int lane = tid & 63, wrow = (tid >> 6) * 32;
    wave_layer<1, 4, true >(buf, wfrag, C_B0, wrow, lane);
    wave_layer<2, 1, false>(buf, wfrag, C_B1, wrow, lane);
    __syncthreads();

    float density = 0.f;
    if (tid < 128) {
        float bb[16];
        const f32x4* bv = reinterpret_cast<const f32x4*>(&buf[(size_t)tid * LDW]);
#pragma unroll
        for (int g4 = 0; g4 < 4; ++g4) {
            const f32x4 v = bv[g4];
#pragma unroll
            for (int j = 0; j < 4; ++j) bb[4 * g4 + j] = v[j];
        }
        const float x0v = xn0[pn], x1v = xn1[pn], x2v = xn2[pn];
        const bool sel = x0v > 0.f && x0v < 1.f && x1v > 0.f && x1v < 1.f &&
                         x2v > 0.f && x2v < 1.f;
        density = sel ? expf(bb[0] - 1.0f) : 0.0f;

        const float ddx = g_dir[3 * pn + 0];
        const float ddy = g_dir[3 * pn + 1];
        const float ddz = g_dir[3 * pn + 2];
        const float nrm = sqrtf(ddx * ddx + ddy * ddy + ddz * ddz);
        const float x = ddx / nrm, y = ddy / nrm, z = ddz / nrm;
        const float xy = x * y, yz = y * z, xz = x * z;
        const float x2 = x * x, y2 = y * y, z2 = z * z;
        f32x4 o0, o1, o2, o3, o4, o5, o6, o7;
        o0[0] = 0.28209479177387814f;
        o0[1] = -0.48860251190291987f * y;
        o0[2] = 0.48860251190291987f * z;
        o0[3] = -0.48860251190291987f * x;
        o1[0] = 1.0925484305920792f * xy;
        o1[1] = -1.0925484305920792f * yz;
        o1[2] = 0.94617469575756f * z2 - 0.31539156525252f;
        o1[3] = -1.0925484305920792f * xz;
        o2[0] = 0.5462742152960396f * (x2 - y2);
        o2[1] = 0.5900435899266435f * y * (y2 - 3.0f * x2);
        o2[2] = 2.890611442640554f * xy * z;
        o2[3] = 0.4570457994644657f * y * (1.0f - 5.0f * z2);
        o3[0] = 0.3731763325901154f * z * (5.0f * z2 - 3.0f);
        o3[1] = 0.4570457994644657f * x * (1.0f - 5.0f * z2);
        o3[2] = 1.445305721320277f * z * (x2 - y2);
        o3[3] = 0.5900435899266435f * x * (3.0f * y2 - x2);
        o4[0] = bb[1];  o4[1] = bb[2];  o4[2] = bb[3];  o4[3] = bb[4];
        o5[0] = bb[5];  o5[1] = bb[6];  o5[2] = bb[7];  o5[3] = bb[8];
        o6[0] = bb[9];  o6[1] = bb[10]; o6[2] = bb[11]; o6[3] = bb[12];
        o7[0] = bb[13]; o7[1] = bb[14]; o7[2] = bb[15]; o7[3] = 0.f;
        f32x4* wb = reinterpret_cast<f32x4*>(&buf[(size_t)tid * LDW]);
        wb[0] = o0; wb[1] = o1; wb[2] = o2; wb[3] = o3;
        wb[4] = o4; wb[5] = o5; wb[6] = o6; wb[7] = o7;
    }
    __syncthreads();

    wave_layer<1, 4, true >(buf, wfrag, C_H0, wrow, lane);
    wave_layer<2, 4, true >(buf, wfrag, C_H1, wrow, lane);
    wave_layer<2, 1, false>(buf, wfrag, C_H2, wrow, lane);
    __syncthreads();

    if (tid < 128 && base + tid < N) {
        const int n = base + tid;
        float4 o;
        o.x = 1.0f / (1.0f + expf(-buf[(size_t)tid * LDW + 0]));
        o.y = 1.0f / (1.0f + expf(-buf[(size_t)tid * LDW + 1]));
        o.z = 1.0f / (1.0f + expf(-buf[(size_t)tid * LDW + 2]));
        o.w = density;
        *reinterpret_cast<float4*>(g_out + (size_t)n * 4) = o;
    }
}

// ---------------------------------------------------------------------------
// Scalar fallback (round-2 monolith) used only if ws too small
// ---------------------------------------------------------------------------
template<int IN, int OUT, bool RELU>
__device__ __forceinline__ void layer(const float* __restrict__ W,
                                      const float* __restrict__ hin,
                                      float* __restrict__ A,
                                      float* __restrict__ out)
{
#pragma unroll
    for (int j = 0; j < OUT; ++j) out[j] = 0.f;
#pragma unroll
    for (int c = 0; c < IN; c += CHUNK) {
#pragma unroll
        for (int i = 0; i < CHUNK; ++i) {
            if (c + i < IN) A[i * TPB] = RELU ? fmaxf(hin[c + i], 0.f) : hin[c + i];
        }
        const int cnt = (IN - c < CHUNK) ? (IN - c) : CHUNK;
#pragma unroll 4
        for (int i = 0; i < cnt; ++i) {
            const float a = A[i * TPB];
            const float* __restrict__ Wr = W + (size_t)(c + i) * OUT;
#pragma unroll
            for (int j = 0; j < OUT; ++j)
                out[j] = fmaf(a, Wr[j], out[j]);
        }
    }
}

__global__ __launch_bounds__(TPB, 4) void dngp_mono(
    const float* __restrict__ g_pos, const float* __restrict__ g_t,
    const float* __restrict__ g_dir, const float* __restrict__ g_tab,
    const float* __restrict__ Ww0, const float* __restrict__ Ww1, const float* __restrict__ Ww2,
    const float* __restrict__ Wb0, const float* __restrict__ Wb1,
    const float* __restrict__ Wh0, const float* __restrict__ Wh1, const float* __restrict__ Wh2,
    float* __restrict__ g_out, int N, LevelParams lp)
{
    __shared__ float s_act[CHUNK * TPB];
    const int tid = threadIdx.x;
    const int n = blockIdx.x * TPB + tid;
    if (n >= N) return;
    float* __restrict__ A = s_act + tid;

    const float px = g_pos[3 * n + 0];
    const float py = g_pos[3 * n + 1];
    const float pz = g_pos[3 * n + 2];
    const float tt = g_t[n];

    float enc[32];
    {
        const float xin[4] = { px, py, pz, tt };
        const float PI_F = 3.14159265358979323846f;
#pragma unroll
        for (int d = 0; d < 4; ++d)
#pragma unroll
            for (int k = 0; k < 4; ++k) {
                float s, c;
                sincosf(xin[d] * (PI_F * (float)(1 << k)), &s, &c);
                enc[d * 8 + k]     = s;
                enc[d * 8 + 4 + k] = c;
            }
    }

    float h[64], h2[64], off[3];
    layer<32, 64, false>(Ww0, enc, A, h);
    layer<64, 64, true >(Ww1, h,   A, h2);
    layer<64, 3,  true >(Ww2, h2,  A, off);

    const float xn[3] = { (px + off[0] * MOVE_STEP + 1.5f) / 3.0f,
                          (py + off[1] * MOVE_STEP + 1.5f) / 3.0f,
                          (pz + off[2] * MOVE_STEP + 1.5f) / 3.0f };
    const bool sel = xn[0] > 0.f && xn[0] < 1.f && xn[1] > 0.f && xn[1] < 1.f &&
                     xn[2] > 0.f && xn[2] < 1.f;

    float feat[32];
#pragma unroll 2
    for (int l = 0; l < N_LVL; ++l) {
        const float scale = lp.scale[l];
        const int res = lp.res[l];
        float fr[3]; int c0[3];
#pragma unroll
        for (int d = 0; d < 3; ++d) {
            const float pp = xn[d] * scale + 0.5f;
            const float fl = floorf(pp);
            fr[d] = pp - fl;
            c0[d] = (int)fl;
        }
        const float* __restrict__ tbl = g_tab + (size_t)l * (size_t)(TBL * 2);
        float f0 = 0.f, f1 = 0.f;
        if (lp.dense[l]) {
#pragma unroll
            for (int c = 0; c < 8; ++c) {
                const int ci = (c >> 2) & 1, cj = (c >> 1) & 1, ck = c & 1;
                const unsigned idx = (unsigned)((c0[0] + ci) + res * ((c0[1] + cj) + res * (c0[2] + ck)));
                const float2 f = *reinterpret_cast<const float2*>(tbl + (size_t)idx * 2);
                const float w = (ci ? fr[0] : 1.f - fr[0]) * (cj ? fr[1] : 1.f - fr[1]) * (ck ? fr[2] : 1.f - fr[2]);
                f0 = fmaf(w, f.x, f0);
                f1 = fmaf(w, f.y, f1);
            }
        } else {
#pragma unroll
            for (int c = 0; c < 8; ++c) {
                const int ci = (c >> 2) & 1, cj = (c >> 1) & 1, ck = c & 1;
                const unsigned hx = (unsigned)(c0[0] + ci);
                const unsigned hy = (unsigned)(c0[1] + cj) * 2654435761u;
                const unsigned hz = (unsigned)(c0[2] + ck) * 805459861u;
                const unsigned idx = (hx ^ hy ^ hz) & (TBL - 1u);
                const float2 f = *reinterpret_cast<const float2*>(tbl + (size_t)idx * 2);
                const float w = (ci ? fr[0] : 1.f - fr[0]) * (cj ? fr[1] : 1.f - fr[1]) * (ck ? fr[2] : 1.f - fr[2]);
                f0 = fmaf(w, f.x, f0);
                f1 = fmaf(w, f.y, f1);
            }
        }
        feat[2 * l]     = f0;
        feat[2 * l + 1] = f1;
    }

    layer<32, 64, false>(Wb0, feat, A, h);
    float b[16];
    layer<64, 16, true >(Wb1, h, A, b);
    const float density = sel ? expf(b[0] - 1.0f) : 0.0f;

    float hin[31];
    {
        const float ddx = g_dir[3 * n + 0];
        const float ddy = g_dir[3 * n + 1];
        const float ddz = g_dir[3 * n + 2];
        const float nrm = sqrtf(ddx * ddx + ddy * ddy + ddz * ddz);
        const float x = ddx / nrm, y = ddy / nrm, z = ddz / nrm;
        const float xy = x * y, yz = y * z, xz = x * z;
        const float x2_ = x * x, y2 = y * y, z2 = z * z;
        hin[0]  = 0.28209479177387814f;
        hin[1]  = -0.48860251190291987f * y;
        hin[2]  = 0.48860251190291987f * z;
        hin[3]  = -0.48860251190291987f * x;
        hin[4]  = 1.0925484305920792f * xy;
        hin[5]  = -1.0925484305920792f * yz;
        hin[6]  = 0.94617469575756f * z2 - 0.31539156525252f;
        hin[7]  = -1.0925484305920792f * xz;
        hin[8]  = 0.5462742152960396f * (x2_ - y2);
        hin[9]  = 0.5900435899266435f * y * (y2 - 3.0f * x2_);
        hin[10] = 2.890611442640554f * xy * z;
        hin[11] = 0.4570457994644657f * y * (1.0f - 5.0f * z2);
        hin[12] = 0.3731763325901154f * z * (5.0f * z2 - 3.0f);
        hin[13] = 0.4570457994644657f * x * (1.0f - 5.0f * z2);
        hin[14] = 1.445305721320277f * z * (x2_ - y2);
        hin[15] = 0.5900435899266435f * x * (3.0f * y2 - x2_);
#pragma unroll
        for (int j = 0; j < 15; ++j) hin[16 + j] = b[1 + j];
    }

    layer<31, 64, false>(Wh0, hin, A, h);
    layer<64, 64, true >(Wh1, h,   A, h2);
    float rgb[3];
    layer<64, 3,  true >(Wh2, h2,  A, rgb);

    float4 o;
    o.x = 1.0f / (1.0f + expf(-rgb[0]));
    o.y = 1.0f / (1.0f + expf(-rgb[1]));
    o.z = 1.0f / (1.0f + expf(-rgb[2]));
    o.w = density;
    *reinterpret_cast<float4*>(g_out + (size_t)n * 4) = o;
}

extern "C" void kernel_launch(void* const* d_in, const int* in_sizes, int n_in,
                              void* d_out, int out_size, void* d_ws, size_t ws_size,
                              hipStream_t stream)
{
    const float* g_pos = (const float*)d_in[0];
    const float* g_t   = (const float*)d_in[1];
    const float* g_dir = (const float*)d_in[2];
    const float* g_tab = (const float*)d_in[3];
    const float* Ww0   = (const float*)d_in[4];
    const float* Ww1   = (const float*)d_in[5];
    const float* Ww2   = (const float*)d_in[6];
    const float* Wb0   = (const float*)d_in[7];
    const float* Wb1   = (const float*)d_in[8];
    const float* Wh0   = (const float*)d_in[9];
    const float* Wh1   = (const float*)d_in[10];
    const float* Wh2   = (const float*)d_in[11];
    const int N = in_sizes[0] / 3;

    LevelParams lp;
    int n_dense = 0;
    const double Bv = exp(log(4096.0 / 16.0) / 15.0);
    for (int l = 0; l < N_LVL; ++l) {
        const double s = 16.0 * pow(Bv, (double)l) - 1.0;
        lp.scale[l] = (float)s;
        const int r = (int)ceil(s) + 1;
        lp.res[l] = r;
        lp.dense[l] = ((long long)r * r * r <= (long long)TBL) ? 1 : 0;
        if (lp.dense[l]) n_dense = l + 1;
    }

    const size_t stride = ((size_t)N + 259) & ~(size_t)3;
    const size_t ws_need = (size_t)C_TOT * 2048 + stride * 4 * (3 + 32);

    if (ws_size >= ws_need) {
        unsigned short* wfrag = (unsigned short*)d_ws;
        float* xn0 = (float*)((char*)d_ws + (size_t)C_TOT * 2048);
        float* xn1 = xn0 + stride;
        float* xn2 = xn1 + stride;
        float* featp = xn2 + stride;                          // 32 f32 planes

        AllLayers al;
        al.L[0] = { Ww0, 32, 64, 1, 4, C_W0 };
        al.L[1] = { Ww1, 64, 64, 2, 4, C_W1 };
        al.L[2] = { Ww2, 64,  3, 2, 1, C_W2 };
        al.L[3] = { Wb0, 32, 64, 1, 4, C_B0 };
        al.L[4] = { Wb1, 64, 16, 2, 1, C_B1 };
        al.L[5] = { Wh0, 31, 64, 1, 4, C_H0 };
        al.L[6] = { Wh1, 64, 64, 2, 4, C_H1 };
        al.L[7] = { Wh2, 64,  3, 2, 1, C_H2 };

        dim3 mgrid((N + 127) / 128), mblock(256);
        dim3 hgrid((N + HTPB * 2 - 1) / (HTPB * 2)), hblock(HTPB);

        hipLaunchKernelGGL(k_prep, dim3(8), dim3(256), 0, stream, al, wfrag);

        hipLaunchKernelGGL(k_warp_mfma, mgrid, mblock, 0, stream,
                           g_pos, g_t, wfrag, xn0, xn1, xn2, N);

        hipLaunchKernelGGL(k_hash_dense, hgrid, hblock, 0, stream,
                           g_tab, xn0, xn1, xn2, featp, stride, N, n_dense, lp);

        for (int l = n_dense; l < N_LVL; ++l) {
            hipLaunchKernelGGL(k_hash_level, hgrid, hblock, 0, stream,
                               g_tab + (size_t)l * (size_t)(TBL * 2),
                               xn0, xn1, xn2,
                               featp + (size_t)(2 * l)     * stride,
                               featp + (size_t)(2 * l + 1) * stride,
                               N, lp.scale[l]);
        }

        hipLaunchKernelGGL(k_final_mfma, mgrid, mblock, 0, stream,
                           featp, stride, xn0, xn1, xn2, g_dir,
                           wfrag, (float*)d_out, N);
    } else {
        dim3 grid((N + TPB - 1) / TPB), block(TPB);
        hipLaunchKernelGGL(dngp_mono, grid, block, 0, stream,
                           g_pos, g_t, g_dir, g_tab,
                           Ww0, Ww1, Ww2, Wb0, Wb1, Wh0, Wh1, Wh2,
                           (float*)d_out, N, lp);
    }
}

// Round 8
// 369.074 us; speedup vs baseline: 1.7742x; 1.0636x over previous
//
#include <hip/hip_runtime.h>
#include <math.h>

#define TPB   128     // scalar fallback
#define HTPB  256
#define CHUNK 32
#define LDW   68      // f32 LDS row stride: 272 B, 16B-aligned
constexpr int  N_LVL = 16;
constexpr unsigned TBL = 1u << 19;
constexpr float MOVE_STEP = 1.0f / 4096.0f;

typedef __attribute__((ext_vector_type(8))) short short8;
typedef __attribute__((ext_vector_type(4))) float f32x4;

struct LevelParams { float scale[N_LVL]; int res[N_LVL]; int dense[N_LVL]; };

// weight-fragment chunks (2048 B each = hi[64 lanes][short8] + lo[...])
enum { C_W0 = 0, C_W1 = 4, C_W2 = 12, C_B0 = 14, C_B1 = 18, C_H0 = 20, C_H1 = 24, C_H2 = 32, C_TOT = 34 };

struct LayerDesc { const float* W; int K; int N; int ksteps; int ntiles; int cbase; };
struct AllLayers { LayerDesc L[8]; };

__device__ __forceinline__ unsigned short f2bf(float x) {
    unsigned int u = __float_as_uint(x);
    u += 0x7FFFu + ((u >> 16) & 1u);            // RNE
    return (unsigned short)(u >> 16);
}
__device__ __forceinline__ float bf2f(unsigned short h) {
    return __uint_as_float(((unsigned int)h) << 16);
}

// hw RNE pack: bf16(a) in [15:0], bf16(b) in [31:16]
__device__ __forceinline__ unsigned cvt_pk_bf16(float a, float b) {
    unsigned r;
    asm("v_cvt_pk_bf16_f32 %0, %1, %2" : "=v"(r) : "v"(a), "v"(b));
    return r;
}
// RNE hi/lo split of a float pair via cvt_pk (6 VALU vs ~20 integer-trick).
// Same RNE rounding as f2bf; residual subtraction exact (Sterbenz).
__device__ __forceinline__ void split_pair(float a, float b, unsigned& hp, unsigned& lp) {
    hp = cvt_pk_bf16(a, b);
    const float ha = __uint_as_float(hp << 16);
    const float hb = __uint_as_float(hp & 0xffff0000u);
    lp = cvt_pk_bf16(a - ha, b - hb);
}

// ---------------------------------------------------------------------------
// prep: split weights into bf16 (hi,lo) MFMA B-fragments (RNE), per-lane order
// ---------------------------------------------------------------------------
__global__ __launch_bounds__(256) void k_prep(AllLayers al, unsigned short* __restrict__ wfrag)
{
    const LayerDesc d = al.L[blockIdx.x];
    const int total = d.ksteps * d.ntiles * 64;
    for (int slot = threadIdx.x; slot < total; slot += 256) {
        const int lane = slot & 63;
        const int c = slot >> 6;
        const int s = c / d.ntiles;
        const int t = c - s * d.ntiles;
        short8 hv, lv;
#pragma unroll
        for (int j = 0; j < 8; ++j) {
            const int k = s * 32 + ((lane >> 4) << 3) + j;
            const int n = t * 16 + (lane & 15);
            const float w = (k < d.K && n < d.N) ? d.W[k * d.N + n] : 0.f;
            const unsigned short hi = f2bf(w);
            const unsigned short lo = f2bf(w - bf2f(hi));
            hv[j] = (short)hi;
            lv[j] = (short)lo;
        }
        short8* b8 = reinterpret_cast<short8*>(wfrag + (size_t)(d.cbase + c) * 1024);
        b8[lane]      = hv;
        b8[64 + lane] = lv;
    }
}

// ---------------------------------------------------------------------------
// wave dense layer: f32 LDS in, per-k-step RNE hi/lo split (cvt_pk), 3-term
// MFMA (hh + lh + hl), f32 LDS out. In-place on one buffer (proven R7).
// ---------------------------------------------------------------------------
template<int KSTEPS, int NTILES, bool RELU>
__device__ __forceinline__ void wave_layer(float* X,
                                           const unsigned short* __restrict__ wfrag, int cbase,
                                           int wrow, int lane)
{
    f32x4 acc[2][NTILES];
#pragma unroll
    for (int ms = 0; ms < 2; ++ms)
#pragma unroll
        for (int t = 0; t < NTILES; ++t) acc[ms][t] = f32x4{0.f, 0.f, 0.f, 0.f};
    const int r15 = lane & 15, q = lane >> 4;
    const short8* wf8 = reinterpret_cast<const short8*>(wfrag) + (size_t)cbase * 128;
#pragma unroll
    for (int s = 0; s < KSTEPS; ++s) {
        short8 ah[2], al[2];
#pragma unroll
        for (int ms = 0; ms < 2; ++ms) {
            const float* xp = X + (size_t)(wrow + ms * 16 + r15) * LDW + s * 32 + q * 8;
            const f32x4 x0 = reinterpret_cast<const f32x4*>(xp)[0];
            const f32x4 x1 = reinterpret_cast<const f32x4*>(xp)[1];
            union { unsigned u[4]; short8 s8; } uh, ul;
            split_pair(x0[0], x0[1], uh.u[0], ul.u[0]);
            split_pair(x0[2], x0[3], uh.u[1], ul.u[1]);
            split_pair(x1[0], x1[1], uh.u[2], ul.u[2]);
            split_pair(x1[2], x1[3], uh.u[3], ul.u[3]);
            ah[ms] = uh.s8;
            al[ms] = ul.s8;
        }
#pragma unroll
        for (int t = 0; t < NTILES; ++t) {
            const short8* cp = wf8 + (size_t)(s * NTILES + t) * 128;
            const short8 bh = cp[lane];
            const short8 bl = cp[64 + lane];
#pragma unroll
            for (int ms = 0; ms < 2; ++ms) {
                acc[ms][t] = __builtin_amdgcn_mfma_f32_16x16x32_bf16(ah[ms], bh, acc[ms][t], 0, 0, 0);
                acc[ms][t] = __builtin_amdgcn_mfma_f32_16x16x32_bf16(al[ms], bh, acc[ms][t], 0, 0, 0);
                acc[ms][t] = __builtin_amdgcn_mfma_f32_16x16x32_bf16(ah[ms], bl, acc[ms][t], 0, 0, 0);
            }
        }
    }
#pragma unroll
    for (int ms = 0; ms < 2; ++ms)
#pragma unroll
        for (int t = 0; t < NTILES; ++t)
#pragma unroll
            for (int r = 0; r < 4; ++r) {
                float v = acc[ms][t][r];
                if (RELU) v = fmaxf(v, 0.f);
                X[(size_t)(wrow + ms * 16 + q * 4 + r) * LDW + t * 16 + r15] = v;
            }
}

// ---------------------------------------------------------------------------
// Kernel 1: freq encode + warp MLP (MFMA) -> xn planes + DENSE hash levels
// (dense gathers fused into epilogue: half-threads do levels 0-2, half 3-4;
//  f32 math identical to the old k_hash_dense)
// ---------------------------------------------------------------------------
__global__ __launch_bounds__(256, 4) void k_warp_mfma(
    const float* __restrict__ g_pos, const float* __restrict__ g_t,
    const float* __restrict__ g_tab,
    const unsigned short* __restrict__ wfrag,
    float* __restrict__ xn0, float* __restrict__ xn1, float* __restrict__ xn2,
    float* __restrict__ featp, size_t stride, int N, int n_dense, LevelParams lp)
{
    __shared__ float buf[128 * LDW];        // 34.8 KB
    const int tid = threadIdx.x;
    const int base = blockIdx.x * 128;
    const int p = tid & 127;
    const int pn = min(base + p, N - 1);
    const float PI_F = 3.14159265358979323846f;

    {   // enc staging: thread-pairs split the 4 input dims
        const int dpair = tid >> 7;
        float v0, v1;
        if (dpair == 0) { v0 = g_pos[3 * pn + 0]; v1 = g_pos[3 * pn + 1]; }
        else            { v0 = g_pos[3 * pn + 2]; v1 = g_t[pn]; }
#pragma unroll
        for (int e = 0; e < 2; ++e) {
            const float x = e ? v1 : v0;
            const int d = dpair * 2 + e;
            f32x4 sv, cv;
#pragma unroll
            for (int k = 0; k < 4; ++k) {
                const float a = x * (PI_F * (float)(1 << k));
                sv[k] = __sinf(a);
                cv[k] = __cosf(a);
            }
            *reinterpret_cast<f32x4*>(&buf[(size_t)p * LDW + d * 8])     = sv;
            *reinterpret_cast<f32x4*>(&buf[(size_t)p * LDW + d * 8 + 4]) = cv;
        }
    }
    __syncthreads();
    const int lane = tid & 63, wrow = (tid >> 6) * 32;
    wave_layer<1, 4, true >(buf, wfrag, C_W0, wrow, lane);
    wave_layer<2, 4, true >(buf, wfrag, C_W1, wrow, lane);
    wave_layer<2, 1, false>(buf, wfrag, C_W2, wrow, lane);
    __syncthreads();

    // ---- epilogue: xn (both halves compute; half 0 stores) + dense levels
    const int n = base + p;
    const float ox = buf[(size_t)p * LDW + 0];
    const float oy = buf[(size_t)p * LDW + 1];
    const float oz = buf[(size_t)p * LDW + 2];
    const float xnv[3] = { (g_pos[3 * pn + 0] + ox * MOVE_STEP + 1.5f) / 3.0f,
                           (g_pos[3 * pn + 1] + oy * MOVE_STEP + 1.5f) / 3.0f,
                           (g_pos[3 * pn + 2] + oz * MOVE_STEP + 1.5f) / 3.0f };
    if (tid < 128 && n < N) {
        xn0[n] = xnv[0];
        xn1[n] = xnv[1];
        xn2[n] = xnv[2];
    }

    const int dmid = min(3, n_dense);
    const int l0 = (tid < 128) ? 0 : dmid;
    const int l1 = (tid < 128) ? dmid : n_dense;
    for (int l = l0; l < l1; ++l) {
        const float scale = lp.scale[l];
        const int res = lp.res[l];
        float fr[3]; int c0[3];
#pragma unroll
        for (int d = 0; d < 3; ++d) {
            const float pp = xnv[d] * scale + 0.5f;
            const float fl = floorf(pp);
            fr[d] = pp - fl;
            c0[d] = (int)fl;
        }
        const float* __restrict__ tbl = g_tab + (size_t)l * (size_t)(TBL * 2);
        float2 v[8];
#pragma unroll
        for (int c = 0; c < 8; ++c) {
            const int ci = (c >> 2) & 1, cj = (c >> 1) & 1, ck = c & 1;
            const unsigned idx = (unsigned)((c0[0] + ci) + res * ((c0[1] + cj) + res * (c0[2] + ck)));
            v[c] = *reinterpret_cast<const float2*>(tbl + (size_t)idx * 2);
        }
        float f0 = 0.f, f1 = 0.f;
#pragma unroll
        for (int c = 0; c < 8; ++c) {
            const int ci = (c >> 2) & 1, cj = (c >> 1) & 1, ck = c & 1;
            const float w = (ci ? fr[0] : 1.f - fr[0])
                          * (cj ? fr[1] : 1.f - fr[1])
                          * (ck ? fr[2] : 1.f - fr[2]);
            f0 = fmaf(w, v[c].x, f0);
            f1 = fmaf(w, v[c].y, f1);
        }
        if (n < N) {
            __builtin_nontemporal_store(f0, &featp[(size_t)(2 * l)     * stride + n]);
            __builtin_nontemporal_store(f1, &featp[(size_t)(2 * l + 1) * stride + n]);
        }
    }
}

// ---------------------------------------------------------------------------
// Kernel 2 (x11): one hashed level, 2 points/thread. nt hints keep the 4MB
// table L2-resident against the xn/feat streams (values unchanged).
// ---------------------------------------------------------------------------
__global__ __launch_bounds__(HTPB) void k_hash_level(
    const float* __restrict__ tbl,
    const float* __restrict__ xn0, const float* __restrict__ xn1,
    const float* __restrict__ xn2,
    float* __restrict__ o0, float* __restrict__ o1, int N, float scale)
{
    const int n0 = blockIdx.x * (HTPB * 2) + threadIdx.x;
    const int n1 = n0 + HTPB;
    const bool a0 = n0 < N, a1 = n1 < N;
    const int m0 = a0 ? n0 : 0, m1 = a1 ? n1 : 0;
    const float xa[3] = { __builtin_nontemporal_load(&xn0[m0]),
                          __builtin_nontemporal_load(&xn1[m0]),
                          __builtin_nontemporal_load(&xn2[m0]) };
    const float xb[3] = { __builtin_nontemporal_load(&xn0[m1]),
                          __builtin_nontemporal_load(&xn1[m1]),
                          __builtin_nontemporal_load(&xn2[m1]) };

    float fra[3], frb[3]; int ca[3], cb[3];
#pragma unroll
    for (int d = 0; d < 3; ++d) {
        float pp = xa[d] * scale + 0.5f, fl = floorf(pp);
        fra[d] = pp - fl; ca[d] = (int)fl;
        pp = xb[d] * scale + 0.5f; fl = floorf(pp);
        frb[d] = pp - fl; cb[d] = (int)fl;
    }
    float2 va[8], vb[8];
#pragma unroll
    for (int c = 0; c < 8; ++c) {
        const int ci = (c >> 2) & 1, cj = (c >> 1) & 1, ck = c & 1;
        const unsigned ia = (((unsigned)(ca[0] + ci)) ^ ((unsigned)(ca[1] + cj) * 2654435761u)
                             ^ ((unsigned)(ca[2] + ck) * 805459861u)) & (TBL - 1u);
        va[c] = *reinterpret_cast<const float2*>(tbl + (size_t)ia * 2);
    }
#pragma unroll
    for (int c = 0; c < 8; ++c) {
        const int ci = (c >> 2) & 1, cj = (c >> 1) & 1, ck = c & 1;
        const unsigned ib = (((unsigned)(cb[0] + ci)) ^ ((unsigned)(cb[1] + cj) * 2654435761u)
                             ^ ((unsigned)(cb[2] + ck) * 805459861u)) & (TBL - 1u);
        vb[c] = *reinterpret_cast<const float2*>(tbl + (size_t)ib * 2);
    }
    float f0a = 0.f, f1a = 0.f, f0b = 0.f, f1b = 0.f;
#pragma unroll
    for (int c = 0; c < 8; ++c) {
        const int ci = (c >> 2) & 1, cj = (c >> 1) & 1, ck = c & 1;
        const float wa = (ci ? fra[0] : 1.f - fra[0]) * (cj ? fra[1] : 1.f - fra[1]) * (ck ? fra[2] : 1.f - fra[2]);
        const float wb = (ci ? frb[0] : 1.f - frb[0]) * (cj ? frb[1] : 1.f - frb[1]) * (ck ? frb[2] : 1.f - frb[2]);
        f0a = fmaf(wa, va[c].x, f0a); f1a = fmaf(wa, va[c].y, f1a);
        f0b = fmaf(wb, vb[c].x, f0b); f1b = fmaf(wb, vb[c].y, f1b);
    }
    if (a0) { __builtin_nontemporal_store(f0a, &o0[n0]); __builtin_nontemporal_store(f1a, &o1[n0]); }
    if (a1) { __builtin_nontemporal_store(f0b, &o0[n1]); __builtin_nontemporal_store(f1b, &o1[n1]); }
}

// ---------------------------------------------------------------------------
// Kernel 3: base MLP + SH + head MLP (MFMA) -> output
// ---------------------------------------------------------------------------
__global__ __launch_bounds__(256, 4) void k_final_mfma(
    const float* __restrict__ featp, size_t stride,
    const float* __restrict__ xn0, const float* __restrict__ xn1,
    const float* __restrict__ xn2,
    const float* __restrict__ g_dir,
    const unsigned short* __restrict__ wfrag,
    float* __restrict__ g_out, int N)
{
    __shared__ float buf[128 * LDW];        // 34.8 KB
    const int tid = threadIdx.x;
    const int base = blockIdx.x * 128;
    const int p = tid & 127;
    const int pn = min(base + p, N - 1);
    const int fb = (tid >> 7) * 16;

    // stage 32 f32 feat planes -> buf[p][0..31]
#pragma unroll
    for (int j = 0; j < 16; ++j)
        buf[(size_t)p * LDW + fb + j] = featp[(size_t)(fb + j) * stride + pn];
    __syncthreads();

    const int lane = tid & 63, wrow = (tid >> 6) * 32;
    wave_layer<1, 4, true >(buf, wfrag, C_B0, wrow, lane);
    wave_layer<2, 1, false>(buf, wfrag, C_B1, wrow, lane);
    __syncthreads();

    float density = 0.f;
    if (tid < 128) {
        float bb[16];
        const f32x4* bv = reinterpret_cast<const f32x4*>(&buf[(size_t)tid * LDW]);
#pragma unroll
        for (int g4 = 0; g4 < 4; ++g4) {
            const f32x4 v = bv[g4];
#pragma unroll
            for (int j = 0; j < 4; ++j) bb[4 * g4 + j] = v[j];
        }
        const float x0v = xn0[pn], x1v = xn1[pn], x2v = xn2[pn];
        const bool sel = x0v > 0.f && x0v < 1.f && x1v > 0.f && x1v < 1.f &&
                         x2v > 0.f && x2v < 1.f;
        density = sel ? expf(bb[0] - 1.0f) : 0.0f;

        const float ddx = g_dir[3 * pn + 0];
        const float ddy = g_dir[3 * pn + 1];
        const float ddz = g_dir[3 * pn + 2];
        const float nrm = sqrtf(ddx * ddx + ddy * ddy + ddz * ddz);
        const float x = ddx / nrm, y = ddy / nrm, z = ddz / nrm;
        const float xy = x * y, yz = y * z, xz = x * z;
        const float x2 = x * x, y2 = y * y, z2 = z * z;
        f32x4 o0, o1, o2, o3, o4, o5, o6, o7;
        o0[0] = 0.28209479177387814f;
        o0[1] = -0.48860251190291987f * y;
        o0[2] = 0.48860251190291987f * z;
        o0[3] = -0.48860251190291987f * x;
        o1[0] = 1.0925484305920792f * xy;
        o1[1] = -1.0925484305920792f * yz;
        o1[2] = 0.94617469575756f * z2 - 0.31539156525252f;
        o1[3] = -1.0925484305920792f * xz;
        o2[0] = 0.5462742152960396f * (x2 - y2);
        o2[1] = 0.5900435899266435f * y * (y2 - 3.0f * x2);
        o2[2] = 2.890611442640554f * xy * z;
        o2[3] = 0.4570457994644657f * y * (1.0f - 5.0f * z2);
        o3[0] = 0.3731763325901154f * z * (5.0f * z2 - 3.0f);
        o3[1] = 0.4570457994644657f * x * (1.0f - 5.0f * z2);
        o3[2] = 1.445305721320277f * z * (x2 - y2);
        o3[3] = 0.5900435899266435f * x * (3.0f * y2 - x2);
        o4[0] = bb[1];  o4[1] = bb[2];  o4[2] = bb[3];  o4[3] = bb[4];
        o5[0] = bb[5];  o5[1] = bb[6];  o5[2] = bb[7];  o5[3] = bb[8];
        o6[0] = bb[9];  o6[1] = bb[10]; o6[2] = bb[11]; o6[3] = bb[12];
        o7[0] = bb[13]; o7[1] = bb[14]; o7[2] = bb[15]; o7[3] = 0.f;
        f32x4* wb = reinterpret_cast<f32x4*>(&buf[(size_t)tid * LDW]);
        wb[0] = o0; wb[1] = o1; wb[2] = o2; wb[3] = o3;
        wb[4] = o4; wb[5] = o5; wb[6] = o6; wb[7] = o7;
    }
    __syncthreads();

    wave_layer<1, 4, true >(buf, wfrag, C_H0, wrow, lane);
    wave_layer<2, 4, true >(buf, wfrag, C_H1, wrow, lane);
    wave_layer<2, 1, false>(buf, wfrag, C_H2, wrow, lane);
    __syncthreads();

    if (tid < 128 && base + tid < N) {
        const int n = base + tid;
        float4 o;
        o.x = 1.0f / (1.0f + expf(-buf[(size_t)tid * LDW + 0]));
        o.y = 1.0f / (1.0f + expf(-buf[(size_t)tid * LDW + 1]));
        o.z = 1.0f / (1.0f + expf(-buf[(size_t)tid * LDW + 2]));
        o.w = density;
        *reinterpret_cast<float4*>(g_out + (size_t)n * 4) = o;
    }
}

// ---------------------------------------------------------------------------
// Scalar fallback (round-2 monolith) used only if ws too small
// ---------------------------------------------------------------------------
template<int IN, int OUT, bool RELU>
__device__ __forceinline__ void layer(const float* __restrict__ W,
                                      const float* __restrict__ hin,
                                      float* __restrict__ A,
                                      float* __restrict__ out)
{
#pragma unroll
    for (int j = 0; j < OUT; ++j) out[j] = 0.f;
#pragma unroll
    for (int c = 0; c < IN; c += CHUNK) {
#pragma unroll
        for (int i = 0; i < CHUNK; ++i) {
            if (c + i < IN) A[i * TPB] = RELU ? fmaxf(hin[c + i], 0.f) : hin[c + i];
        }
        const int cnt = (IN - c < CHUNK) ? (IN - c) : CHUNK;
#pragma unroll 4
        for (int i = 0; i < cnt; ++i) {
            const float a = A[i * TPB];
            const float* __restrict__ Wr = W + (size_t)(c + i) * OUT;
#pragma unroll
            for (int j = 0; j < OUT; ++j)
                out[j] = fmaf(a, Wr[j], out[j]);
        }
    }
}

__global__ __launch_bounds__(TPB, 4) void dngp_mono(
    const float* __restrict__ g_pos, const float* __restrict__ g_t,
    const float* __restrict__ g_dir, const float* __restrict__ g_tab,
    const float* __restrict__ Ww0, const float* __restrict__ Ww1, const float* __restrict__ Ww2,
    const float* __restrict__ Wb0, const float* __restrict__ Wb1,
    const float* __restrict__ Wh0, const float* __restrict__ Wh1, const float* __restrict__ Wh2,
    float* __restrict__ g_out, int N, LevelParams lp)
{
    __shared__ float s_act[CHUNK * TPB];
    const int tid = threadIdx.x;
    const int n = blockIdx.x * TPB + tid;
    if (n >= N) return;
    float* __restrict__ A = s_act + tid;

    const float px = g_pos[3 * n + 0];
    const float py = g_pos[3 * n + 1];
    const float pz = g_pos[3 * n + 2];
    const float tt = g_t[n];

    float enc[32];
    {
        const float xin[4] = { px, py, pz, tt };
        const float PI_F = 3.14159265358979323846f;
#pragma unroll
        for (int d = 0; d < 4; ++d)
#pragma unroll
            for (int k = 0; k < 4; ++k) {
                float s, c;
                sincosf(xin[d] * (PI_F * (float)(1 << k)), &s, &c);
                enc[d * 8 + k]     = s;
                enc[d * 8 + 4 + k] = c;
            }
    }

    float h[64], h2[64], off[3];
    layer<32, 64, false>(Ww0, enc, A, h);
    layer<64, 64, true >(Ww1, h,   A, h2);
    layer<64, 3,  true >(Ww2, h2,  A, off);

    const float xn[3] = { (px + off[0] * MOVE_STEP + 1.5f) / 3.0f,
                          (py + off[1] * MOVE_STEP + 1.5f) / 3.0f,
                          (pz + off[2] * MOVE_STEP + 1.5f) / 3.0f };
    const bool sel = xn[0] > 0.f && xn[0] < 1.f && xn[1] > 0.f && xn[1] < 1.f &&
                     xn[2] > 0.f && xn[2] < 1.f;

    float feat[32];
#pragma unroll 2
    for (int l = 0; l < N_LVL; ++l) {
        const float scale = lp.scale[l];
        const int res = lp.res[l];
        float fr[3]; int c0[3];
#pragma unroll
        for (int d = 0; d < 3; ++d) {
            const float pp = xn[d] * scale + 0.5f;
            const float fl = floorf(pp);
            fr[d] = pp - fl;
            c0[d] = (int)fl;
        }
        const float* __restrict__ tbl = g_tab + (size_t)l * (size_t)(TBL * 2);
        float f0 = 0.f, f1 = 0.f;
        if (lp.dense[l]) {
#pragma unroll
            for (int c = 0; c < 8; ++c) {
                const int ci = (c >> 2) & 1, cj = (c >> 1) & 1, ck = c & 1;
                const unsigned idx = (unsigned)((c0[0] + ci) + res * ((c0[1] + cj) + res * (c0[2] + ck)));
                const float2 f = *reinterpret_cast<const float2*>(tbl + (size_t)idx * 2);
                const float w = (ci ? fr[0] : 1.f - fr[0]) * (cj ? fr[1] : 1.f - fr[1]) * (ck ? fr[2] : 1.f - fr[2]);
                f0 = fmaf(w, f.x, f0);
                f1 = fmaf(w, f.y, f1);
            }
        } else {
#pragma unroll
            for (int c = 0; c < 8; ++c) {
                const int ci = (c >> 2) & 1, cj = (c >> 1) & 1, ck = c & 1;
                const unsigned hx = (unsigned)(c0[0] + ci);
                const unsigned hy = (unsigned)(c0[1] + cj) * 2654435761u;
                const unsigned hz = (unsigned)(c0[2] + ck) * 805459861u;
                const unsigned idx = (hx ^ hy ^ hz) & (TBL - 1u);
                const float2 f = *reinterpret_cast<const float2*>(tbl + (size_t)idx * 2);
                const float w = (ci ? fr[0] : 1.f - fr[0]) * (cj ? fr[1] : 1.f - fr[1]) * (ck ? fr[2] : 1.f - fr[2]);
                f0 = fmaf(w, f.x, f0);
                f1 = fmaf(w, f.y, f1);
            }
        }
        feat[2 * l]     = f0;
        feat[2 * l + 1] = f1;
    }

    layer<32, 64, false>(Wb0, feat, A, h);
    float b[16];
    layer<64, 16, true >(Wb1, h, A, b);
    const float density = sel ? expf(b[0] - 1.0f) : 0.0f;

    float hin[31];
    {
        const float ddx = g_dir[3 * n + 0];
        const float ddy = g_dir[3 * n + 1];
        const float ddz = g_dir[3 * n + 2];
        const float nrm = sqrtf(ddx * ddx + ddy * ddy + ddz * ddz);
        const float x = ddx / nrm, y = ddy / nrm, z = ddz / nrm;
        const float xy = x * y, yz = y * z, xz = x * z;
        const float x2_ = x * x, y2 = y * y, z2 = z * z;
        hin[0]  = 0.28209479177387814f;
        hin[1]  = -0.48860251190291987f * y;
        hin[2]  = 0.48860251190291987f * z;
        hin[3]  = -0.48860251190291987f * x;
        hin[4]  = 1.0925484305920792f * xy;
        hin[5]  = -1.0925484305920792f * yz;
        hin[6]  = 0.94617469575756f * z2 - 0.31539156525252f;
        hin[7]  = -1.0925484305920792f * xz;
        hin[8]  = 0.5462742152960396f * (x2_ - y2);
        hin[9]  = 0.5900435899266435f * y * (y2 - 3.0f * x2_);
        hin[10] = 2.890611442640554f * xy * z;
        hin[11] = 0.4570457994644657f * y * (1.0f - 5.0f * z2);
        hin[12] = 0.3731763325901154f * z * (5.0f * z2 - 3.0f);
        hin[13] = 0.4570457994644657f * x * (1.0f - 5.0f * z2);
        hin[14] = 1.445305721320277f * z * (x2_ - y2);
        hin[15] = 0.5900435899266435f * x * (3.0f * y2 - x2_);
#pragma unroll
        for (int j = 0; j < 15; ++j) hin[16 + j] = b[1 + j];
    }

    layer<31, 64, false>(Wh0, hin, A, h);
    layer<64, 64, true >(Wh1, h,   A, h2);
    float rgb[3];
    layer<64, 3,  true >(Wh2, h2,  A, rgb);

    float4 o;
    o.x = 1.0f / (1.0f + expf(-rgb[0]));
    o.y = 1.0f / (1.0f + expf(-rgb[1]));
    o.z = 1.0f / (1.0f + expf(-rgb[2]));
    o.w = density;
    *reinterpret_cast<float4*>(g_out + (size_t)n * 4) = o;
}

extern "C" void kernel_launch(void* const* d_in, const int* in_sizes, int n_in,
                              void* d_out, int out_size, void* d_ws, size_t ws_size,
                              hipStream_t stream)
{
    const float* g_pos = (const float*)d_in[0];
    const float* g_t   = (const float*)d_in[1];
    const float* g_dir = (const float*)d_in[2];
    const float* g_tab = (const float*)d_in[3];
    const float* Ww0   = (const float*)d_in[4];
    const float* Ww1   = (const float*)d_in[5];
    const float* Ww2   = (const float*)d_in[6];
    const float* Wb0   = (const float*)d_in[7];
    const float* Wb1   = (const float*)d_in[8];
    const float* Wh0   = (const float*)d_in[9];
    const float* Wh1   = (const float*)d_in[10];
    const float* Wh2   = (const float*)d_in[11];
    const int N = in_sizes[0] / 3;

    LevelParams lp;
    int n_dense = 0;
    const double Bv = exp(log(4096.0 / 16.0) / 15.0);
    for (int l = 0; l < N_LVL; ++l) {
        const double s = 16.0 * pow(Bv, (double)l) - 1.0;
        lp.scale[l] = (float)s;
        const int r = (int)ceil(s) + 1;
        lp.res[l] = r;
        lp.dense[l] = ((long long)r * r * r <= (long long)TBL) ? 1 : 0;
        if (lp.dense[l]) n_dense = l + 1;
    }

    const size_t stride = ((size_t)N + 259) & ~(size_t)3;
    const size_t ws_need = (size_t)C_TOT * 2048 + stride * 4 * (3 + 32);

    if (ws_size >= ws_need) {
        unsigned short* wfrag = (unsigned short*)d_ws;
        float* xn0 = (float*)((char*)d_ws + (size_t)C_TOT * 2048);
        float* xn1 = xn0 + stride;
        float* xn2 = xn1 + stride;
        float* featp = xn2 + stride;                          // 32 f32 planes

        AllLayers al;
        al.L[0] = { Ww0, 32, 64, 1, 4, C_W0 };
        al.L[1] = { Ww1, 64, 64, 2, 4, C_W1 };
        al.L[2] = { Ww2, 64,  3, 2, 1, C_W2 };
        al.L[3] = { Wb0, 32, 64, 1, 4, C_B0 };
        al.L[4] = { Wb1, 64, 16, 2, 1, C_B1 };
        al.L[5] = { Wh0, 31, 64, 1, 4, C_H0 };
        al.L[6] = { Wh1, 64, 64, 2, 4, C_H1 };
        al.L[7] = { Wh2, 64,  3, 2, 1, C_H2 };

        dim3 mgrid((N + 127) / 128), mblock(256);
        dim3 hgrid((N + HTPB * 2 - 1) / (HTPB * 2)), hblock(HTPB);

        hipLaunchKernelGGL(k_prep, dim3(8), dim3(256), 0, stream, al, wfrag);

        hipLaunchKernelGGL(k_warp_mfma, mgrid, mblock, 0, stream,
                           g_pos, g_t, g_tab, wfrag, xn0, xn1, xn2,
                           featp, stride, N, n_dense, lp);

        for (int l = n_dense; l < N_LVL; ++l) {
            hipLaunchKernelGGL(k_hash_level, hgrid, hblock, 0, stream,
                               g_tab + (size_t)l * (size_t)(TBL * 2),
                               xn0, xn1, xn2,
                               featp + (size_t)(2 * l)     * stride,
                               featp + (size_t)(2 * l + 1) * stride,
                               N, lp.scale[l]);
        }

        hipLaunchKernelGGL(k_final_mfma, mgrid, mblock, 0, stream,
                           featp, stride, xn0, xn1, xn2, g_dir,
                           wfrag, (float*)d_out, N);
    } else {
        dim3 grid((N + TPB - 1) / TPB), block(TPB);
        hipLaunchKernelGGL(dngp_mono, grid, block, 0, stream,
                           g_pos, g_t, g_dir, g_tab,
                           Ww0, Ww1, Ww2, Wb0, Wb1, Wh0, Wh1, Wh2,
                           (float*)d_out, N, lp);
    }
}

// Round 9
// 355.286 us; speedup vs baseline: 1.8430x; 1.0388x over previous
//
#include <hip/hip_runtime.h>
#include <math.h>

#define TPB   128     // scalar fallback
#define HTPB  256
#define HPTS  4       // points per thread in hash kernel
#define CHUNK 32
#define LDW   68      // f32 LDS row stride: 272 B, 16B-aligned
constexpr int  N_LVL = 16;
constexpr unsigned TBL = 1u << 19;
constexpr float MOVE_STEP = 1.0f / 4096.0f;

typedef __attribute__((ext_vector_type(8))) short short8;
typedef __attribute__((ext_vector_type(4))) float f32x4;

struct LevelParams { float scale[N_LVL]; int res[N_LVL]; int dense[N_LVL]; };

// weight-fragment chunks (2048 B each = hi[64 lanes][short8] + lo[...])
enum { C_W0 = 0, C_W1 = 4, C_W2 = 12, C_B0 = 14, C_B1 = 18, C_H0 = 20, C_H1 = 24, C_H2 = 32, C_TOT = 34 };

struct LayerDesc { const float* W; int K; int N; int ksteps; int ntiles; int cbase; };
struct AllLayers { LayerDesc L[8]; };

__device__ __forceinline__ unsigned short f2bf(float x) {
    unsigned int u = __float_as_uint(x);
    u += 0x7FFFu + ((u >> 16) & 1u);            // RNE
    return (unsigned short)(u >> 16);
}
__device__ __forceinline__ float bf2f(unsigned short h) {
    return __uint_as_float(((unsigned int)h) << 16);
}

// hw RNE pack: bf16(a) in [15:0], bf16(b) in [31:16]
__device__ __forceinline__ unsigned cvt_pk_bf16(float a, float b) {
    unsigned r;
    asm("v_cvt_pk_bf16_f32 %0, %1, %2" : "=v"(r) : "v"(a), "v"(b));
    return r;
}
// RNE hi/lo split of a float pair via cvt_pk. Same RNE as f2bf; residual exact.
__device__ __forceinline__ void split_pair(float a, float b, unsigned& hp, unsigned& lp) {
    hp = cvt_pk_bf16(a, b);
    const float ha = __uint_as_float(hp << 16);
    const float hb = __uint_as_float(hp & 0xffff0000u);
    lp = cvt_pk_bf16(a - ha, b - hb);
}

// ---------------------------------------------------------------------------
// prep: split weights into bf16 (hi,lo) MFMA B-fragments (RNE), per-lane order
// ---------------------------------------------------------------------------
__global__ __launch_bounds__(256) void k_prep(AllLayers al, unsigned short* __restrict__ wfrag)
{
    const LayerDesc d = al.L[blockIdx.x];
    const int total = d.ksteps * d.ntiles * 64;
    for (int slot = threadIdx.x; slot < total; slot += 256) {
        const int lane = slot & 63;
        const int c = slot >> 6;
        const int s = c / d.ntiles;
        const int t = c - s * d.ntiles;
        short8 hv, lv;
#pragma unroll
        for (int j = 0; j < 8; ++j) {
            const int k = s * 32 + ((lane >> 4) << 3) + j;
            const int n = t * 16 + (lane & 15);
            const float w = (k < d.K && n < d.N) ? d.W[k * d.N + n] : 0.f;
            const unsigned short hi = f2bf(w);
            const unsigned short lo = f2bf(w - bf2f(hi));
            hv[j] = (short)hi;
            lv[j] = (short)lo;
        }
        short8* b8 = reinterpret_cast<short8*>(wfrag + (size_t)(d.cbase + c) * 1024);
        b8[lane]      = hv;
        b8[64 + lane] = lv;
    }
}

// ---------------------------------------------------------------------------
// wave dense layer: f32 LDS in, per-k-step RNE hi/lo split (cvt_pk), 3-term
// MFMA (hh + lh + hl), f32 LDS out. In-place on one buffer (proven R7).
// ---------------------------------------------------------------------------
template<int KSTEPS, int NTILES, bool RELU>
__device__ __forceinline__ void wave_layer(float* X,
                                           const unsigned short* __restrict__ wfrag, int cbase,
                                           int wrow, int lane)
{
    f32x4 acc[2][NTILES];
#pragma unroll
    for (int ms = 0; ms < 2; ++ms)
#pragma unroll
        for (int t = 0; t < NTILES; ++t) acc[ms][t] = f32x4{0.f, 0.f, 0.f, 0.f};
    const int r15 = lane & 15, q = lane >> 4;
    const short8* wf8 = reinterpret_cast<const short8*>(wfrag) + (size_t)cbase * 128;
#pragma unroll
    for (int s = 0; s < KSTEPS; ++s) {
        short8 ah[2], al[2];
#pragma unroll
        for (int ms = 0; ms < 2; ++ms) {
            const float* xp = X + (size_t)(wrow + ms * 16 + r15) * LDW + s * 32 + q * 8;
            const f32x4 x0 = reinterpret_cast<const f32x4*>(xp)[0];
            const f32x4 x1 = reinterpret_cast<const f32x4*>(xp)[1];
            union { unsigned u[4]; short8 s8; } uh, ul;
            split_pair(x0[0], x0[1], uh.u[0], ul.u[0]);
            split_pair(x0[2], x0[3], uh.u[1], ul.u[1]);
            split_pair(x1[0], x1[1], uh.u[2], ul.u[2]);
            split_pair(x1[2], x1[3], uh.u[3], ul.u[3]);
            ah[ms] = uh.s8;
            al[ms] = ul.s8;
        }
#pragma unroll
        for (int t = 0; t < NTILES; ++t) {
            const short8* cp = wf8 + (size_t)(s * NTILES + t) * 128;
            const short8 bh = cp[lane];
            const short8 bl = cp[64 + lane];
#pragma unroll
            for (int ms = 0; ms < 2; ++ms) {
                acc[ms][t] = __builtin_amdgcn_mfma_f32_16x16x32_bf16(ah[ms], bh, acc[ms][t], 0, 0, 0);
                acc[ms][t] = __builtin_amdgcn_mfma_f32_16x16x32_bf16(al[ms], bh, acc[ms][t], 0, 0, 0);
                acc[ms][t] = __builtin_amdgcn_mfma_f32_16x16x32_bf16(ah[ms], bl, acc[ms][t], 0, 0, 0);
            }
        }
    }
#pragma unroll
    for (int ms = 0; ms < 2; ++ms)
#pragma unroll
        for (int t = 0; t < NTILES; ++t)
#pragma unroll
            for (int r = 0; r < 4; ++r) {
                float v = acc[ms][t][r];
                if (RELU) v = fmaxf(v, 0.f);
                X[(size_t)(wrow + ms * 16 + q * 4 + r) * LDW + t * 16 + r15] = v;
            }
}

// ---------------------------------------------------------------------------
// Kernel 1: freq encode + warp MLP (MFMA) -> xn planes + DENSE hash levels
// ---------------------------------------------------------------------------
__global__ __launch_bounds__(256, 4) void k_warp_mfma(
    const float* __restrict__ g_pos, const float* __restrict__ g_t,
    const float* __restrict__ g_tab,
    const unsigned short* __restrict__ wfrag,
    float* __restrict__ xn0, float* __restrict__ xn1, float* __restrict__ xn2,
    float* __restrict__ featp, size_t stride, int N, int n_dense, LevelParams lp)
{
    __shared__ float buf[128 * LDW];        // 34.8 KB
    const int tid = threadIdx.x;
    const int base = blockIdx.x * 128;
    const int p = tid & 127;
    const int pn = min(base + p, N - 1);
    const float PI_F = 3.14159265358979323846f;

    {   // enc staging: thread-pairs split the 4 input dims
        const int dpair = tid >> 7;
        float v0, v1;
        if (dpair == 0) { v0 = g_pos[3 * pn + 0]; v1 = g_pos[3 * pn + 1]; }
        else            { v0 = g_pos[3 * pn + 2]; v1 = g_t[pn]; }
#pragma unroll
        for (int e = 0; e < 2; ++e) {
            const float x = e ? v1 : v0;
            const int d = dpair * 2 + e;
            f32x4 sv, cv;
#pragma unroll
            for (int k = 0; k < 4; ++k) {
                const float a = x * (PI_F * (float)(1 << k));
                sv[k] = __sinf(a);
                cv[k] = __cosf(a);
            }
            *reinterpret_cast<f32x4*>(&buf[(size_t)p * LDW + d * 8])     = sv;
            *reinterpret_cast<f32x4*>(&buf[(size_t)p * LDW + d * 8 + 4]) = cv;
        }
    }
    __syncthreads();
    const int lane = tid & 63, wrow = (tid >> 6) * 32;
    wave_layer<1, 4, true >(buf, wfrag, C_W0, wrow, lane);
    wave_layer<2, 4, true >(buf, wfrag, C_W1, wrow, lane);
    wave_layer<2, 1, false>(buf, wfrag, C_W2, wrow, lane);
    __syncthreads();

    // ---- epilogue: xn (both halves compute; half 0 stores) + dense levels
    const int n = base + p;
    const float ox = buf[(size_t)p * LDW + 0];
    const float oy = buf[(size_t)p * LDW + 1];
    const float oz = buf[(size_t)p * LDW + 2];
    const float xnv[3] = { (g_pos[3 * pn + 0] + ox * MOVE_STEP + 1.5f) / 3.0f,
                           (g_pos[3 * pn + 1] + oy * MOVE_STEP + 1.5f) / 3.0f,
                           (g_pos[3 * pn + 2] + oz * MOVE_STEP + 1.5f) / 3.0f };
    if (tid < 128 && n < N) {
        xn0[n] = xnv[0];
        xn1[n] = xnv[1];
        xn2[n] = xnv[2];
    }

    const int dmid = min(3, n_dense);
    const int l0 = (tid < 128) ? 0 : dmid;
    const int l1 = (tid < 128) ? dmid : n_dense;
    for (int l = l0; l < l1; ++l) {
        const float scale = lp.scale[l];
        const int res = lp.res[l];
        float fr[3]; int c0[3];
#pragma unroll
        for (int d = 0; d < 3; ++d) {
            const float pp = xnv[d] * scale + 0.5f;
            const float fl = floorf(pp);
            fr[d] = pp - fl;
            c0[d] = (int)fl;
        }
        const float* __restrict__ tbl = g_tab + (size_t)l * (size_t)(TBL * 2);
        float2 v[8];
#pragma unroll
        for (int c = 0; c < 8; ++c) {
            const int ci = (c >> 2) & 1, cj = (c >> 1) & 1, ck = c & 1;
            const unsigned idx = (unsigned)((c0[0] + ci) + res * ((c0[1] + cj) + res * (c0[2] + ck)));
            v[c] = *reinterpret_cast<const float2*>(tbl + (size_t)idx * 2);
        }
        float f0 = 0.f, f1 = 0.f;
#pragma unroll
        for (int c = 0; c < 8; ++c) {
            const int ci = (c >> 2) & 1, cj = (c >> 1) & 1, ck = c & 1;
            const float w = (ci ? fr[0] : 1.f - fr[0])
                          * (cj ? fr[1] : 1.f - fr[1])
                          * (ck ? fr[2] : 1.f - fr[2]);
            f0 = fmaf(w, v[c].x, f0);
            f1 = fmaf(w, v[c].y, f1);
        }
        if (n < N) {
            __builtin_nontemporal_store(f0, &featp[(size_t)(2 * l)     * stride + n]);
            __builtin_nontemporal_store(f1, &featp[(size_t)(2 * l + 1) * stride + n]);
        }
    }
}

// ---------------------------------------------------------------------------
// Kernel 2: ALL hashed levels in one launch. gridDim.y = n_levels; blocks are
// bid-linearized x-fastest, so each level's 512 blocks dispatch contiguously
// -> at any instant ~1-2 levels active chip-wide -> per-XCD L2 holds ~1 table
// (preserves the per-level L2 residency win) with zero inter-launch gaps.
// 4 points/thread = 32 gathers in flight. f32 math identical to before.
// ---------------------------------------------------------------------------
__global__ __launch_bounds__(HTPB) void k_hash_all(
    const float* __restrict__ g_tab,
    const float* __restrict__ xn0, const float* __restrict__ xn1,
    const float* __restrict__ xn2,
    float* __restrict__ featp, size_t stride, int N, int n_dense, LevelParams lp)
{
    const int l = n_dense + blockIdx.y;
    const float scale = lp.scale[l];
    const float* __restrict__ tbl = g_tab + (size_t)l * (size_t)(TBL * 2);
    float* __restrict__ o0 = featp + (size_t)(2 * l)     * stride;
    float* __restrict__ o1 = featp + (size_t)(2 * l + 1) * stride;

    const int base = blockIdx.x * (HTPB * HPTS) + threadIdx.x;

    int nn[HPTS]; bool av[HPTS];
    float xs[HPTS][3];
#pragma unroll
    for (int k = 0; k < HPTS; ++k) {
        nn[k] = base + k * HTPB;
        av[k] = nn[k] < N;
        const int m = av[k] ? nn[k] : 0;
        xs[k][0] = __builtin_nontemporal_load(&xn0[m]);
        xs[k][1] = __builtin_nontemporal_load(&xn1[m]);
        xs[k][2] = __builtin_nontemporal_load(&xn2[m]);
    }

    float fr[HPTS][3];
    float2 v[HPTS][8];
#pragma unroll
    for (int k = 0; k < HPTS; ++k) {
        int c0[3];
#pragma unroll
        for (int d = 0; d < 3; ++d) {
            const float pp = xs[k][d] * scale + 0.5f;
            const float fl = floorf(pp);
            fr[k][d] = pp - fl;
            c0[d] = (int)fl;
        }
#pragma unroll
        for (int c = 0; c < 8; ++c) {
            const int ci = (c >> 2) & 1, cj = (c >> 1) & 1, ck = c & 1;
            const unsigned idx = (((unsigned)(c0[0] + ci)) ^ ((unsigned)(c0[1] + cj) * 2654435761u)
                                  ^ ((unsigned)(c0[2] + ck) * 805459861u)) & (TBL - 1u);
            v[k][c] = *reinterpret_cast<const float2*>(tbl + (size_t)idx * 2);
        }
    }

#pragma unroll
    for (int k = 0; k < HPTS; ++k) {
        float f0 = 0.f, f1 = 0.f;
#pragma unroll
        for (int c = 0; c < 8; ++c) {
            const int ci = (c >> 2) & 1, cj = (c >> 1) & 1, ck = c & 1;
            const float w = (ci ? fr[k][0] : 1.f - fr[k][0])
                          * (cj ? fr[k][1] : 1.f - fr[k][1])
                          * (ck ? fr[k][2] : 1.f - fr[k][2]);
            f0 = fmaf(w, v[k][c].x, f0);
            f1 = fmaf(w, v[k][c].y, f1);
        }
        if (av[k]) {
            __builtin_nontemporal_store(f0, &o0[nn[k]]);
            __builtin_nontemporal_store(f1, &o1[nn[k]]);
        }
    }
}

// ---------------------------------------------------------------------------
// Kernel 3: base MLP + SH + head MLP (MFMA) -> output
// ---------------------------------------------------------------------------
__global__ __launch_bounds__(256, 4) void k_final_mfma(
    const float* __restrict__ featp, size_t stride,
    const float* __restrict__ xn0, const float* __restrict__ xn1,
    const float* __restrict__ xn2,
    const float* __restrict__ g_dir,
    const unsigned short* __restrict__ wfrag,
    float* __restrict__ g_out, int N)
{
    __shared__ float buf[128 * LDW];        // 34.8 KB
    const int tid = threadIdx.x;
    const int base = blockIdx.x * 128;
    const int p = tid & 127;
    const int pn = min(base + p, N - 1);
    const int fb = (tid >> 7) * 16;

    // stage 32 f32 feat planes -> buf[p][0..31]
#pragma unroll
    for (int j = 0; j < 16; ++j)
        buf[(size_t)p * LDW + fb + j] = featp[(size_t)(fb + j) * stride + pn];
    __syncthreads();

    const int lane = tid & 63, wrow = (tid >> 6) * 32;
    wave_layer<1, 4, true >(buf, wfrag, C_B0, wrow, lane);
    wave_layer<2, 1, false>(buf, wfrag, C_B1, wrow, lane);
    __syncthreads();

    float density = 0.f;
    if (tid < 128) {
        float bb[16];
        const f32x4* bv = reinterpret_cast<const f32x4*>(&buf[(size_t)tid * LDW]);
#pragma unroll
        for (int g4 = 0; g4 < 4; ++g4) {
            const f32x4 v = bv[g4];
#pragma unroll
            for (int j = 0; j < 4; ++j) bb[4 * g4 + j] = v[j];
        }
        const float x0v = xn0[pn], x1v = xn1[pn], x2v = xn2[pn];
        const bool sel = x0v > 0.f && x0v < 1.f && x1v > 0.f && x1v < 1.f &&
                         x2v > 0.f && x2v < 1.f;
        density = sel ? expf(bb[0] - 1.0f) : 0.0f;

        const float ddx = g_dir[3 * pn + 0];
        const float ddy = g_dir[3 * pn + 1];
        const float ddz = g_dir[3 * pn + 2];
        const float nrm = sqrtf(ddx * ddx + ddy * ddy + ddz * ddz);
        const float x = ddx / nrm, y = ddy / nrm, z = ddz / nrm;
        const float xy = x * y, yz = y * z, xz = x * z;
        const float x2 = x * x, y2 = y * y, z2 = z * z;
        f32x4 o0, o1, o2, o3, o4, o5, o6, o7;
        o0[0] = 0.28209479177387814f;
        o0[1] = -0.48860251190291987f * y;
        o0[2] = 0.48860251190291987f * z;
        o0[3] = -0.48860251190291987f * x;
        o1[0] = 1.0925484305920792f * xy;
        o1[1] = -1.0925484305920792f * yz;
        o1[2] = 0.94617469575756f * z2 - 0.31539156525252f;
        o1[3] = -1.0925484305920792f * xz;
        o2[0] = 0.5462742152960396f * (x2 - y2);
        o2[1] = 0.5900435899266435f * y * (y2 - 3.0f * x2);
        o2[2] = 2.890611442640554f * xy * z;
        o2[3] = 0.4570457994644657f * y * (1.0f - 5.0f * z2);
        o3[0] = 0.3731763325901154f * z * (5.0f * z2 - 3.0f);
        o3[1] = 0.4570457994644657f * x * (1.0f - 5.0f * z2);
        o3[2] = 1.445305721320277f * z * (x2 - y2);
        o3[3] = 0.5900435899266435f * x * (3.0f * y2 - x2);
        o4[0] = bb[1];  o4[1] = bb[2];  o4[2] = bb[3];  o4[3] = bb[4];
        o5[0] = bb[5];  o5[1] = bb[6];  o5[2] = bb[7];  o5[3] = bb[8];
        o6[0] = bb[9];  o6[1] = bb[10]; o6[2] = bb[11]; o6[3] = bb[12];
        o7[0] = bb[13]; o7[1] = bb[14]; o7[2] = bb[15]; o7[3] = 0.f;
        f32x4* wb = reinterpret_cast<f32x4*>(&buf[(size_t)tid * LDW]);
        wb[0] = o0; wb[1] = o1; wb[2] = o2; wb[3] = o3;
        wb[4] = o4; wb[5] = o5; wb[6] = o6; wb[7] = o7;
    }
    __syncthreads();

    wave_layer<1, 4, true >(buf, wfrag, C_H0, wrow, lane);
    wave_layer<2, 4, true >(buf, wfrag, C_H1, wrow, lane);
    wave_layer<2, 1, false>(buf, wfrag, C_H2, wrow, lane);
    __syncthreads();

    if (tid < 128 && base + tid < N) {
        const int n = base + tid;
        float4 o;
        o.x = 1.0f / (1.0f + expf(-buf[(size_t)tid * LDW + 0]));
        o.y = 1.0f / (1.0f + expf(-buf[(size_t)tid * LDW + 1]));
        o.z = 1.0f / (1.0f + expf(-buf[(size_t)tid * LDW + 2]));
        o.w = density;
        *reinterpret_cast<float4*>(g_out + (size_t)n * 4) = o;
    }
}

// ---------------------------------------------------------------------------
// Scalar fallback (round-2 monolith) used only if ws too small
// ---------------------------------------------------------------------------
template<int IN, int OUT, bool RELU>
__device__ __forceinline__ void layer(const float* __restrict__ W,
                                      const float* __restrict__ hin,
                                      float* __restrict__ A,
                                      float* __restrict__ out)
{
#pragma unroll
    for (int j = 0; j < OUT; ++j) out[j] = 0.f;
#pragma unroll
    for (int c = 0; c < IN; c += CHUNK) {
#pragma unroll
        for (int i = 0; i < CHUNK; ++i) {
            if (c + i < IN) A[i * TPB] = RELU ? fmaxf(hin[c + i], 0.f) : hin[c + i];
        }
        const int cnt = (IN - c < CHUNK) ? (IN - c) : CHUNK;
#pragma unroll 4
        for (int i = 0; i < cnt; ++i) {
            const float a = A[i * TPB];
            const float* __restrict__ Wr = W + (size_t)(c + i) * OUT;
#pragma unroll
            for (int j = 0; j < OUT; ++j)
                out[j] = fmaf(a, Wr[j], out[j]);
        }
    }
}

__global__ __launch_bounds__(TPB, 4) void dngp_mono(
    const float* __restrict__ g_pos, const float* __restrict__ g_t,
    const float* __restrict__ g_dir, const float* __restrict__ g_tab,
    const float* __restrict__ Ww0, const float* __restrict__ Ww1, const float* __restrict__ Ww2,
    const float* __restrict__ Wb0, const float* __restrict__ Wb1,
    const float* __restrict__ Wh0, const float* __restrict__ Wh1, const float* __restrict__ Wh2,
    float* __restrict__ g_out, int N, LevelParams lp)
{
    __shared__ float s_act[CHUNK * TPB];
    const int tid = threadIdx.x;
    const int n = blockIdx.x * TPB + tid;
    if (n >= N) return;
    float* __restrict__ A = s_act + tid;

    const float px = g_pos[3 * n + 0];
    const float py = g_pos[3 * n + 1];
    const float pz = g_pos[3 * n + 2];
    const float tt = g_t[n];

    float enc[32];
    {
        const float xin[4] = { px, py, pz, tt };
        const float PI_F = 3.14159265358979323846f;
#pragma unroll
        for (int d = 0; d < 4; ++d)
#pragma unroll
            for (int k = 0; k < 4; ++k) {
                float s, c;
                sincosf(xin[d] * (PI_F * (float)(1 << k)), &s, &c);
                enc[d * 8 + k]     = s;
                enc[d * 8 + 4 + k] = c;
            }
    }

    float h[64], h2[64], off[3];
    layer<32, 64, false>(Ww0, enc, A, h);
    layer<64, 64, true >(Ww1, h,   A, h2);
    layer<64, 3,  true >(Ww2, h2,  A, off);

    const float xn[3] = { (px + off[0] * MOVE_STEP + 1.5f) / 3.0f,
                          (py + off[1] * MOVE_STEP + 1.5f) / 3.0f,
                          (pz + off[2] * MOVE_STEP + 1.5f) / 3.0f };
    const bool sel = xn[0] > 0.f && xn[0] < 1.f && xn[1] > 0.f && xn[1] < 1.f &&
                     xn[2] > 0.f && xn[2] < 1.f;

    float feat[32];
#pragma unroll 2
    for (int l = 0; l < N_LVL; ++l) {
        const float scale = lp.scale[l];
        const int res = lp.res[l];
        float fr[3]; int c0[3];
#pragma unroll
        for (int d = 0; d < 3; ++d) {
            const float pp = xn[d] * scale + 0.5f;
            const float fl = floorf(pp);
            fr[d] = pp - fl;
            c0[d] = (int)fl;
        }
        const float* __restrict__ tbl = g_tab + (size_t)l * (size_t)(TBL * 2);
        float f0 = 0.f, f1 = 0.f;
        if (lp.dense[l]) {
#pragma unroll
            for (int c = 0; c < 8; ++c) {
                const int ci = (c >> 2) & 1, cj = (c >> 1) & 1, ck = c & 1;
                const unsigned idx = (unsigned)((c0[0] + ci) + res * ((c0[1] + cj) + res * (c0[2] + ck)));
                const float2 f = *reinterpret_cast<const float2*>(tbl + (size_t)idx * 2);
                const float w = (ci ? fr[0] : 1.f - fr[0]) * (cj ? fr[1] : 1.f - fr[1]) * (ck ? fr[2] : 1.f - fr[2]);
                f0 = fmaf(w, f.x, f0);
                f1 = fmaf(w, f.y, f1);
            }
        } else {
#pragma unroll
            for (int c = 0; c < 8; ++c) {
                const int ci = (c >> 2) & 1, cj = (c >> 1) & 1, ck = c & 1;
                const unsigned hx = (unsigned)(c0[0] + ci);
                const unsigned hy = (unsigned)(c0[1] + cj) * 2654435761u;
                const unsigned hz = (unsigned)(c0[2] + ck) * 805459861u;
                const unsigned idx = (hx ^ hy ^ hz) & (TBL - 1u);
                const float2 f = *reinterpret_cast<const float2*>(tbl + (size_t)idx * 2);
                const float w = (ci ? fr[0] : 1.f - fr[0]) * (cj ? fr[1] : 1.f - fr[1]) * (ck ? fr[2] : 1.f - fr[2]);
                f0 = fmaf(w, f.x, f0);
                f1 = fmaf(w, f.y, f1);
            }
        }
        feat[2 * l]     = f0;
        feat[2 * l + 1] = f1;
    }

    layer<32, 64, false>(Wb0, feat, A, h);
    float b[16];
    layer<64, 16, true >(Wb1, h, A, b);
    const float density = sel ? expf(b[0] - 1.0f) : 0.0f;

    float hin[31];
    {
        const float ddx = g_dir[3 * n + 0];
        const float ddy = g_dir[3 * n + 1];
        const float ddz = g_dir[3 * n + 2];
        const float nrm = sqrtf(ddx * ddx + ddy * ddy + ddz * ddz);
        const float x = ddx / nrm, y = ddy / nrm, z = ddz / nrm;
        const float xy = x * y, yz = y * z, xz = x * z;
        const float x2_ = x * x, y2 = y * y, z2 = z * z;
        hin[0]  = 0.28209479177387814f;
        hin[1]  = -0.48860251190291987f * y;
        hin[2]  = 0.48860251190291987f * z;
        hin[3]  = -0.48860251190291987f * x;
        hin[4]  = 1.0925484305920792f * xy;
        hin[5]  = -1.0925484305920792f * yz;
        hin[6]  = 0.94617469575756f * z2 - 0.31539156525252f;
        hin[7]  = -1.0925484305920792f * xz;
        hin[8]  = 0.5462742152960396f * (x2_ - y2);
        hin[9]  = 0.5900435899266435f * y * (y2 - 3.0f * x2_);
        hin[10] = 2.890611442640554f * xy * z;
        hin[11] = 0.4570457994644657f * y * (1.0f - 5.0f * z2);
        hin[12] = 0.3731763325901154f * z * (5.0f * z2 - 3.0f);
        hin[13] = 0.4570457994644657f * x * (1.0f - 5.0f * z2);
        hin[14] = 1.445305721320277f * z * (x2_ - y2);
        hin[15] = 0.5900435899266435f * x * (3.0f * y2 - x2_);
#pragma unroll
        for (int j = 0; j < 15; ++j) hin[16 + j] = b[1 + j];
    }

    layer<31, 64, false>(Wh0, hin, A, h);
    layer<64, 64, true >(Wh1, h,   A, h2);
    float rgb[3];
    layer<64, 3,  true >(Wh2, h2,  A, rgb);

    float4 o;
    o.x = 1.0f / (1.0f + expf(-rgb[0]));
    o.y = 1.0f / (1.0f + expf(-rgb[1]));
    o.z = 1.0f / (1.0f + expf(-rgb[2]));
    o.w = density;
    *reinterpret_cast<float4*>(g_out + (size_t)n * 4) = o;
}

extern "C" void kernel_launch(void* const* d_in, const int* in_sizes, int n_in,
                              void* d_out, int out_size, void* d_ws, size_t ws_size,
                              hipStream_t stream)
{
    const float* g_pos = (const float*)d_in[0];
    const float* g_t   = (const float*)d_in[1];
    const float* g_dir = (const float*)d_in[2];
    const float* g_tab = (const float*)d_in[3];
    const float* Ww0   = (const float*)d_in[4];
    const float* Ww1   = (const float*)d_in[5];
    const float* Ww2   = (const float*)d_in[6];
    const float* Wb0   = (const float*)d_in[7];
    const float* Wb1   = (const float*)d_in[8];
    const float* Wh0   = (const float*)d_in[9];
    const float* Wh1   = (const float*)d_in[10];
    const float* Wh2   = (const float*)d_in[11];
    const int N = in_sizes[0] / 3;

    LevelParams lp;
    int n_dense = 0;
    const double Bv = exp(log(4096.0 / 16.0) / 15.0);
    for (int l = 0; l < N_LVL; ++l) {
        const double s = 16.0 * pow(Bv, (double)l) - 1.0;
        lp.scale[l] = (float)s;
        const int r = (int)ceil(s) + 1;
        lp.res[l] = r;
        lp.dense[l] = ((long long)r * r * r <= (long long)TBL) ? 1 : 0;
        if (lp.dense[l]) n_dense = l + 1;
    }

    const size_t stride = ((size_t)N + 259) & ~(size_t)3;
    const size_t ws_need = (size_t)C_TOT * 2048 + stride * 4 * (3 + 32);

    if (ws_size >= ws_need) {
        unsigned short* wfrag = (unsigned short*)d_ws;
        float* xn0 = (float*)((char*)d_ws + (size_t)C_TOT * 2048);
        float* xn1 = xn0 + stride;
        float* xn2 = xn1 + stride;
        float* featp = xn2 + stride;                          // 32 f32 planes

        AllLayers al;
        al.L[0] = { Ww0, 32, 64, 1, 4, C_W0 };
        al.L[1] = { Ww1, 64, 64, 2, 4, C_W1 };
        al.L[2] = { Ww2, 64,  3, 2, 1, C_W2 };
        al.L[3] = { Wb0, 32, 64, 1, 4, C_B0 };
        al.L[4] = { Wb1, 64, 16, 2, 1, C_B1 };
        al.L[5] = { Wh0, 31, 64, 1, 4, C_H0 };
        al.L[6] = { Wh1, 64, 64, 2, 4, C_H1 };
        al.L[7] = { Wh2, 64,  3, 2, 1, C_H2 };

        dim3 mgrid((N + 127) / 128), mblock(256);
        dim3 hgrid((N + HTPB * HPTS - 1) / (HTPB * HPTS), N_LVL - n_dense), hblock(HTPB);

        hipLaunchKernelGGL(k_prep, dim3(8), dim3(256), 0, stream, al, wfrag);

        hipLaunchKernelGGL(k_warp_mfma, mgrid, mblock, 0, stream,
                           g_pos, g_t, g_tab, wfrag, xn0, xn1, xn2,
                           featp, stride, N, n_dense, lp);

        hipLaunchKernelGGL(k_hash_all, hgrid, hblock, 0, stream,
                           g_tab, xn0, xn1, xn2, featp, stride, N, n_dense, lp);

        hipLaunchKernelGGL(k_final_mfma, mgrid, mblock, 0, stream,
                           featp, stride, xn0, xn1, xn2, g_dir,
                           wfrag, (float*)d_out, N);
    } else {
        dim3 grid((N + TPB - 1) / TPB), block(TPB);
        hipLaunchKernelGGL(dngp_mono, grid, block, 0, stream,
                           g_pos, g_t, g_dir, g_tab,
                           Ww0, Ww1, Ww2, Wb0, Wb1, Wh0, Wh1, Wh2,
                           (float*)d_out, N, lp);
    }
}